// Round 3
// baseline (91747.955 us; speedup 1.0000x reference)
//
#include <hip/hip_runtime.h>
#include <hip/hip_cooperative_groups.h>
#include <math.h>

namespace cg = cooperative_groups;

#define Bsz 256
#define Tsz 512
#define Hsz 1024

using half8 = __attribute__((ext_vector_type(8))) _Float16;
using half4 = __attribute__((ext_vector_type(4))) _Float16;
using f32x4 = __attribute__((ext_vector_type(4))) float;

#define MFMA(a, b, c) __builtin_amdgcn_mfma_f32_16x16x32_f16(a, b, c, 0, 0, 0)
#define INV2048 (1.0f / 2048.0f)

__device__ __forceinline__ float sigm(float v)   { return 1.0f / (1.0f + expf(-v)); }
__device__ __forceinline__ float tanh_f(float v) { float e = expf(2.0f * v); return 1.0f - 2.0f / (e + 1.0f); }

// ---------------------------------------------------------------------------
// Persistent 2-layer LSTM. 256 blocks x 512 threads (1 block/CU, 8 waves).
// Block owns hidden units ho..ho+3 of BOTH layers (16 permuted gate-rows:
// perm row p = hidoff*4 + gate). Weights live in VGPRs as pre-split fp16
// hi/lo A-fragments (96 VGPR/wave), loaded once before the t-loop.
// Per step: gates accumulated in LDS via K-split (8 waves) + ds atomicAdd;
// cell state c1/c2 resident in LDS; h1/h2 ping-pong in global ws as [b][k]
// fp16 hi/lo; out = b_out + sum(partials) reduced one step late by wave 0.
// ---------------------------------------------------------------------------
__global__ __launch_bounds__(512, 2) void lstm_persist(
    const float* __restrict__ x,
    const float* __restrict__ W_ih1, const float* __restrict__ W_hh1,
    const float* __restrict__ b_ih1, const float* __restrict__ b_hh1,
    const float* __restrict__ W_ih2, const float* __restrict__ W_hh2,
    const float* __restrict__ b_ih2, const float* __restrict__ b_hh2,
    const float* __restrict__ W_out, const float* __restrict__ b_out,
    float* __restrict__ out, char* __restrict__ ws)
{
    __shared__ float gA[16 * 256];   // phase-A gate accumulator [perm row][b]
    __shared__ float gB[16 * 256];   // phase-B gate accumulator
    __shared__ float c1s[4 * 256];   // cell state, layer 1 [hf][b]
    __shared__ float c2s[4 * 256];
    __shared__ float b1p[16], b2p[16], wihp[16], woutp[4], bouts;

    cg::grid_group grid = cg::this_grid();

    const int tid  = threadIdx.x;
    const int lane = tid & 63;
    const int wv   = tid >> 6;        // 0..7 (K-split index)
    const int m    = lane & 15;       // A: M-row / B: N-col
    const int quad = lane >> 4;
    const int bx   = blockIdx.x;      // 256 blocks
    const int ho   = bx << 2;         // 4 hidden units per block

    // ---- workspace layout -------------------------------------------------
    float*    xT      = (float*)ws;                       // [512][256] fp32
    _Float16* hbase   = (_Float16*)(ws + (512 << 10));    // 2 parity regions
    const int HB      = 256 * 1024;                       // halves per buffer
    // region(par): [h1hi | h1lo | h2hi | h2lo], each HB halves
    float*    partials = (float*)(ws + (512 << 10) + (size_t)8 * HB * 2); // [cu][b]

    // ---- pre-loop: params, zeroing, x transpose, weight preload -----------
    if (tid < 16) {
        int row = ((tid & 3) << 10) + ho + (tid >> 2);    // orig W row for perm row tid
        b1p[tid]  = b_ih1[row] + b_hh1[row];
        b2p[tid]  = b_ih2[row] + b_hh2[row];
        wihp[tid] = W_ih1[row];
        if (tid < 4) woutp[tid] = W_out[ho + tid];
        if (tid == 0) bouts = b_out[0];
    }
    {   // zero c-state LDS
        for (int i = tid; i < 1024; i += 512) { c1s[i] = 0.0f; c2s[i] = 0.0f; }
        // zero parity-0 h region (2 MB) : exactly one float4 per thread
        const int gidx = bx * 512 + tid;
        *(float4*)((char*)hbase + (size_t)gidx * 16) = make_float4(0, 0, 0, 0);
        // transpose x -> xT[t][b]
        xT[gidx] = x[(gidx & 255) * Tsz + (gidx >> 8)];
    }

    // weight preload into VGPRs (per-wave K-split A-fragments, perm rows)
    const int rowA = ((m & 3) << 10) + ho + (m >> 2);     // orig row in [4096]
    half8 wAh[4], wAl[4], wBh[8], wBl[8];
    #pragma unroll
    for (int kt = 0; kt < 4; ++kt) {                      // phase A, K=1024
        const int k0 = (wv << 7) + (kt << 5) + (quad << 3);
        const float* p = W_hh1 + (size_t)rowA * 1024 + k0;
        float4 v0 = *(const float4*)p, v1 = *(const float4*)(p + 4);
        float vv[8] = {v0.x, v0.y, v0.z, v0.w, v1.x, v1.y, v1.z, v1.w};
        half8 hi, lo;
        #pragma unroll
        for (int j = 0; j < 8; ++j) {
            hi[j] = (_Float16)vv[j];
            lo[j] = (_Float16)((vv[j] - (float)hi[j]) * 2048.0f);
        }
        wAh[kt] = hi; wAl[kt] = lo;
    }
    #pragma unroll
    for (int kt = 0; kt < 8; ++kt) {                      // phase B, K=2048
        const int k = (wv << 8) + (kt << 5) + (quad << 3);
        const float* p = (k < 1024) ? (W_ih2 + (size_t)rowA * 1024 + k)
                                    : (W_hh2 + (size_t)rowA * 1024 + (k - 1024));
        float4 v0 = *(const float4*)p, v1 = *(const float4*)(p + 4);
        float vv[8] = {v0.x, v0.y, v0.z, v0.w, v1.x, v1.y, v1.z, v1.w};
        half8 hi, lo;
        #pragma unroll
        for (int j = 0; j < 8; ++j) {
            hi[j] = (_Float16)vv[j];
            lo[j] = (_Float16)((vv[j] - (float)hi[j]) * 2048.0f);
        }
        wBh[kt] = hi; wBl[kt] = lo;
    }

    grid.sync();

    // ---- time loop --------------------------------------------------------
    for (int t = 0; t < Tsz; ++t) {
        const int par = t & 1;
        _Float16* h1prevHi = hbase + (size_t)par * 4 * HB;
        _Float16* h1prevLo = h1prevHi + HB;
        _Float16* h2prevHi = h1prevHi + 2 * HB;
        _Float16* h2prevLo = h1prevHi + 3 * HB;
        _Float16* h1curHi  = hbase + (size_t)(par ^ 1) * 4 * HB;
        _Float16* h1curLo  = h1curHi + HB;
        _Float16* h2curHi  = h1curHi + 2 * HB;
        _Float16* h2curLo  = h1curHi + 3 * HB;

        // gate-accumulator init
        #pragma unroll
        for (int i = 0; i < 8; ++i) {
            const int idx = (i << 9) + tid;               // 0..4095
            const int p = idx >> 8, b = idx & 255;
            gA[idx] = b1p[p] + xT[(t << 8) + b] * wihp[p];
            gB[idx] = b2p[p];
        }
        // out-reduction for step t-1 (wave 0; block bx owns batch element bx)
        if (wv == 0 && t > 0) {
            float s = 0.0f;
            #pragma unroll
            for (int i = 0; i < 4; ++i) s += partials[((lane + (i << 6)) << 8) + bx];
            s += __shfl_xor(s, 32); s += __shfl_xor(s, 16); s += __shfl_xor(s, 8);
            s += __shfl_xor(s, 4);  s += __shfl_xor(s, 2);  s += __shfl_xor(s, 1);
            if (lane == 0) out[(bx << 9) + (t - 1)] = bouts + s;
        }
        __syncthreads();

        // ---- phase A MFMA: gates1 += Whh1_perm . h1prev (wave K-split) ----
        #pragma unroll 2
        for (int bi = 0; bi < 16; ++bi) {
            const int bt = (bi + (wv << 1)) & 15;         // stagger -> no LDS-atomic clash
            const int b0 = bt << 4;
            const _Float16* ph = h1prevHi + (((b0 + m) << 10) + (wv << 7) + (quad << 3));
            const _Float16* pl = h1prevLo + (((b0 + m) << 10) + (wv << 7) + (quad << 3));
            f32x4 a0 = {0, 0, 0, 0}, a1 = {0, 0, 0, 0};
            #pragma unroll
            for (int kt = 0; kt < 4; ++kt) {
                const half8 bh = *(const half8*)(ph + (kt << 5));
                const half8 bl = *(const half8*)(pl + (kt << 5));
                a0 = MFMA(wAh[kt], bh, a0);
                a1 = MFMA(wAh[kt], bl, a1);
                a1 = MFMA(wAl[kt], bh, a1);
            }
            #pragma unroll
            for (int r = 0; r < 4; ++r)
                atomicAdd(&gA[((((quad << 2) + r)) << 8) + b0 + m], a0[r] + a1[r] * INV2048);
        }
        __syncthreads();

        // ---- layer-1 cell update ------------------------------------------
        if (tid < 256) {
            const int b = tid;
            half4 hhi, hlo;
            #pragma unroll
            for (int hf = 0; hf < 4; ++hf) {
                const float gi = gA[((hf << 2) + 0) * 256 + b];
                const float gf = gA[((hf << 2) + 1) * 256 + b];
                const float gg = gA[((hf << 2) + 2) * 256 + b];
                const float go = gA[((hf << 2) + 3) * 256 + b];
                const float c  = sigm(gf) * c1s[(hf << 8) + b] + sigm(gi) * tanh_f(gg);
                c1s[(hf << 8) + b] = c;
                const float hn = sigm(go) * tanh_f(c);
                const _Float16 hh = (_Float16)hn;
                hhi[hf] = hh;
                hlo[hf] = (_Float16)((hn - (float)hh) * 2048.0f);
            }
            *(half4*)(h1curHi + (b << 10) + ho) = hhi;
            *(half4*)(h1curLo + (b << 10) + ho) = hlo;
        }
        grid.sync();   // h1cur visible device-wide

        // ---- phase B MFMA: gates2 += W2_perm . [h1cur ; h2prev] -----------
        {
            const _Float16* srcHi = (wv < 4) ? h1curHi : h2prevHi;
            const _Float16* srcLo = (wv < 4) ? h1curLo : h2prevLo;
            const int kofs = (wv < 4) ? (wv << 8) : ((wv << 8) - 1024);
            #pragma unroll 2
            for (int bi = 0; bi < 16; ++bi) {
                const int bt = (bi + (wv << 1)) & 15;
                const int b0 = bt << 4;
                const _Float16* ph = srcHi + (((b0 + m) << 10) + kofs + (quad << 3));
                const _Float16* pl = srcLo + (((b0 + m) << 10) + kofs + (quad << 3));
                f32x4 a0 = {0, 0, 0, 0}, a1 = {0, 0, 0, 0};
                #pragma unroll
                for (int kt = 0; kt < 8; ++kt) {
                    const half8 bh = *(const half8*)(ph + (kt << 5));
                    const half8 bl = *(const half8*)(pl + (kt << 5));
                    a0 = MFMA(wBh[kt], bh, a0);
                    a1 = MFMA(wBh[kt], bl, a1);
                    a1 = MFMA(wBl[kt], bh, a1);
                }
                #pragma unroll
                for (int r = 0; r < 4; ++r)
                    atomicAdd(&gB[((((quad << 2) + r)) << 8) + b0 + m], a0[r] + a1[r] * INV2048);
            }
        }
        __syncthreads();

        // ---- layer-2 cell update + out partial ----------------------------
        if (tid < 256) {
            const int b = tid;
            half4 hhi, hlo;
            float po = 0.0f;
            #pragma unroll
            for (int hf = 0; hf < 4; ++hf) {
                const float gi = gB[((hf << 2) + 0) * 256 + b];
                const float gf = gB[((hf << 2) + 1) * 256 + b];
                const float gg = gB[((hf << 2) + 2) * 256 + b];
                const float go = gB[((hf << 2) + 3) * 256 + b];
                const float c  = sigm(gf) * c2s[(hf << 8) + b] + sigm(gi) * tanh_f(gg);
                c2s[(hf << 8) + b] = c;
                const float hn = sigm(go) * tanh_f(c);
                const _Float16 hh = (_Float16)hn;
                hhi[hf] = hh;
                hlo[hf] = (_Float16)((hn - (float)hh) * 2048.0f);
                po += hn * woutp[hf];
            }
            *(half4*)(h2curHi + (b << 10) + ho) = hhi;
            *(half4*)(h2curLo + (b << 10) + ho) = hlo;
            partials[(bx << 8) + b] = po;
        }
        grid.sync();   // h2cur + partials visible
    }

    // final output column (t = 511)
    if (wv == 0) {
        float s = 0.0f;
        #pragma unroll
        for (int i = 0; i < 4; ++i) s += partials[((lane + (i << 6)) << 8) + bx];
        s += __shfl_xor(s, 32); s += __shfl_xor(s, 16); s += __shfl_xor(s, 8);
        s += __shfl_xor(s, 4);  s += __shfl_xor(s, 2);  s += __shfl_xor(s, 1);
        if (lane == 0) out[(bx << 9) + (Tsz - 1)] = bouts + s;
    }
}

// ---------------------------------------------------------------------------
extern "C" void kernel_launch(void* const* d_in, const int* in_sizes, int n_in,
                              void* d_out, int out_size, void* d_ws, size_t ws_size,
                              hipStream_t stream)
{
    const float* x     = (const float*)d_in[0];
    const float* W_ih1 = (const float*)d_in[1];
    const float* W_hh1 = (const float*)d_in[2];
    const float* b_ih1 = (const float*)d_in[3];
    const float* b_hh1 = (const float*)d_in[4];
    const float* W_ih2 = (const float*)d_in[5];
    const float* W_hh2 = (const float*)d_in[6];
    const float* b_ih2 = (const float*)d_in[7];
    const float* b_hh2 = (const float*)d_in[8];
    const float* W_out = (const float*)d_in[9];
    const float* b_out = (const float*)d_in[10];
    float* out = (float*)d_out;
    char*  ws  = (char*)d_ws;

    void* args[] = {
        (void*)&x,
        (void*)&W_ih1, (void*)&W_hh1, (void*)&b_ih1, (void*)&b_hh1,
        (void*)&W_ih2, (void*)&W_hh2, (void*)&b_ih2, (void*)&b_hh2,
        (void*)&W_out, (void*)&b_out, (void*)&out, (void*)&ws,
    };
    hipLaunchCooperativeKernel((const void*)lstm_persist,
                               dim3(256), dim3(512), args, 0, stream);
}

// Round 4
// 64207.074 us; speedup vs baseline: 1.4289x; 1.4289x over previous
//
#include <hip/hip_runtime.h>
#include <hip/hip_cooperative_groups.h>
#include <math.h>

namespace cg = cooperative_groups;

#define Bsz 256
#define Tsz 512
#define Hsz 1024
#define GSTRIDE 258   // gA/gB row stride (floats): 2-way LDS bank alias only (free)

using half8 = __attribute__((ext_vector_type(8))) _Float16;
using half4 = __attribute__((ext_vector_type(4))) _Float16;
using f32x4 = __attribute__((ext_vector_type(4))) float;

#define MFMA(a, b, c) __builtin_amdgcn_mfma_f32_16x16x32_f16(a, b, c, 0, 0, 0)
#define INV2048 (1.0f / 2048.0f)

__device__ __forceinline__ float sigm(float v)   { return 1.0f / (1.0f + expf(-v)); }
__device__ __forceinline__ float tanh_f(float v) { float e = expf(2.0f * v); return 1.0f - 2.0f / (e + 1.0f); }

// Lightweight grid barrier: monotonic counter in global ws. All 256 blocks
// co-resident (cooperative launch). Leader: release-add (flushes XCD L2),
// relaxed spin, acquire-load (invalidates L1+L2). Block is CU-local so the
// leader's cache ops cover all its waves.
__device__ __forceinline__ void grid_barrier(unsigned* bar, unsigned target) {
    __syncthreads();
    if (threadIdx.x == 0) {
        __hip_atomic_fetch_add(bar, 1u, __ATOMIC_RELEASE, __HIP_MEMORY_SCOPE_AGENT);
        while (__hip_atomic_load(bar, __ATOMIC_RELAXED, __HIP_MEMORY_SCOPE_AGENT) < target)
            __builtin_amdgcn_s_sleep(1);
        (void)__hip_atomic_load(bar, __ATOMIC_ACQUIRE, __HIP_MEMORY_SCOPE_AGENT);
    }
    __syncthreads();
}

// ---------------------------------------------------------------------------
// Persistent 2-layer LSTM, software-pipelined: iteration it runs layer-1
// MFMA for t=it AND layer-2 MFMA for t=it-1 between consecutive barriers
// (1 grid barrier per step). Weights VGPR-resident (split-fp16 hi/lo).
// h1/h2 exchanged via global ws in MFMA-fragment-swizzled layout:
//   h[b][k] lives at buf[bt=b>>4][kc=k>>5][lane=(b&15)|(((k>>3)&3)<<4)][k&7]
// so B-fragment loads are fully coalesced 1KB wave-loads.
// Cell state c1/c2 in registers of threads tid<256 (thread == batch b).
// ---------------------------------------------------------------------------
__global__ __launch_bounds__(512, 2) void lstm_persist(
    const float* __restrict__ x,
    const float* __restrict__ W_ih1, const float* __restrict__ W_hh1,
    const float* __restrict__ b_ih1, const float* __restrict__ b_hh1,
    const float* __restrict__ W_ih2, const float* __restrict__ W_hh2,
    const float* __restrict__ b_ih2, const float* __restrict__ b_hh2,
    const float* __restrict__ W_out, const float* __restrict__ b_out,
    float* __restrict__ out, char* __restrict__ ws)
{
    __shared__ float gA[16 * GSTRIDE];   // layer-1 gate accum [perm row][b]
    __shared__ float gB[16 * GSTRIDE];   // layer-2 gate accum
    __shared__ float b1p[16], b2p[16], wihp[16], woutp[4], bouts_s;

    cg::grid_group grid = cg::this_grid();

    const int tid  = threadIdx.x;
    const int lane = tid & 63;
    const int wv   = tid >> 6;        // 0..7 : K-split index
    const int m    = lane & 15;
    const int quad = lane >> 4;
    const int bx   = blockIdx.x;      // 256 blocks; block bx owns hid ho..ho+3 and batch elem bx's output row
    const int ho   = bx << 2;

    // ---- workspace layout -------------------------------------------------
    float*    xT       = (float*)ws;                                  // [512][256] fp32 (512 KB)
    _Float16* hswz     = (_Float16*)(ws + (512 << 10));               // 8 x 512 KB swizzled h buffers
    float*    partials = (float*)(ws + (512 << 10) + (4 << 20));      // [2 parity][256 cu][256 b]
    unsigned* bar      = (unsigned*)(ws + (512 << 10) + (4 << 20) + (512 << 10));

    // swizzled buffer base: parity p, layer l (0/1), half hl (0=hi,1=lo)
    #define HBUF(p, l, hl) (hswz + ((((p) << 2) | ((l) << 1) | (hl)) << 18))

    // ---- pre-loop init ----------------------------------------------------
    if (bx == 0 && tid == 0) *bar = 0u;
    if (tid < 16) {
        int row = ((tid & 3) << 10) + ho + (tid >> 2);   // perm row tid -> orig W row
        b1p[tid]  = b_ih1[row] + b_hh1[row];
        b2p[tid]  = b_ih2[row] + b_hh2[row];
        wihp[tid] = W_ih1[row];
        if (tid < 4) woutp[tid] = W_out[ho + tid];
        if (tid == 0) bouts_s = b_out[0];
    }
    {
        const int gidx = bx * 512 + tid;                 // 0..131071
        // zero parity-1 h region (initial states h1(-1), h2(-1)): bytes [2MB, 4MB)
        *(float4*)((char*)hswz + (2u << 20) + (size_t)gidx * 16) = make_float4(0, 0, 0, 0);
        // transpose x -> xT[t][b]
        xT[gidx] = x[(gidx & 255) * Tsz + (gidx >> 8)];
    }

    // ---- weight preload into VGPRs (split fp16 hi/lo, per-wave K-slice) ---
    const int rowA = ((m & 3) << 10) + ho + (m >> 2);    // perm row m -> orig row
    half8 wAh[4], wAl[4], wBh[8], wBl[8];
    #pragma unroll
    for (int kt = 0; kt < 4; ++kt) {                     // layer 1, K=1024
        const int k0 = (wv << 7) + (kt << 5) + (quad << 3);
        const float* p = W_hh1 + (size_t)rowA * 1024 + k0;
        float4 v0 = *(const float4*)p, v1 = *(const float4*)(p + 4);
        float vv[8] = {v0.x, v0.y, v0.z, v0.w, v1.x, v1.y, v1.z, v1.w};
        half8 hi, lo;
        #pragma unroll
        for (int j = 0; j < 8; ++j) {
            hi[j] = (_Float16)vv[j];
            lo[j] = (_Float16)((vv[j] - (float)hi[j]) * 2048.0f);
        }
        wAh[kt] = hi; wAl[kt] = lo;
    }
    #pragma unroll
    for (int kt = 0; kt < 8; ++kt) {                     // layer 2, K=2048
        const int k = (wv << 8) + (kt << 5) + (quad << 3);
        const float* p = (k < 1024) ? (W_ih2 + (size_t)rowA * 1024 + k)
                                    : (W_hh2 + (size_t)rowA * 1024 + (k - 1024));
        float4 v0 = *(const float4*)p, v1 = *(const float4*)(p + 4);
        float vv[8] = {v0.x, v0.y, v0.z, v0.w, v1.x, v1.y, v1.z, v1.w};
        half8 hi, lo;
        #pragma unroll
        for (int j = 0; j < 8; ++j) {
            hi[j] = (_Float16)vv[j];
            lo[j] = (_Float16)((vv[j] - (float)hi[j]) * 2048.0f);
        }
        wBh[kt] = hi; wBl[kt] = lo;
    }

    grid.sync();   // one-time heavy sync; makes xT, zeros, bar visible

    // gA/gB init for it=0 (needs xT[0][:], visible post-sync)
    #pragma unroll
    for (int i = 0; i < 8; ++i) {
        const int idx = (i << 9) + tid;                  // 0..4095
        const int p = idx >> 8, b = idx & 255;
        gA[p * GSTRIDE + b] = b1p[p] + xT[b] * wihp[p];
        gB[p * GSTRIDE + b] = b2p[p];
    }
    __syncthreads();

    float c1r[4] = {0, 0, 0, 0}, c2r[4] = {0, 0, 0, 0};

    // cell-update swizzle-write offset for thread b=tid (<256), k-run ho..ho+3
    const int wofs = ((tid & 255) >> 4 << 14) + ((ho >> 5) << 9)
                   + ((((tid & 255) & 15) | (((ho >> 3) & 3) << 4)) << 3) + (ho & 7);

    // ---- main loop: 513 iterations, one grid barrier each -----------------
    for (int it = 0; it <= Tsz; ++it) {
        const int parW = it & 1;        // parity written this iteration (h1(it))
        const int parR = parW ^ 1;      // parity of h1(it-1) / h2(it-1)-write

        // prefetch x for t=it+1 (used in gA re-init at epilogue)
        float xnext = 0.0f;
        if (tid < 256 && it + 1 < Tsz) xnext = xT[((it + 1) << 8) + tid];

        // out-reduction for t = it-2 (partials visible since last barrier)
        if (wv == 0 && it >= 2) {
            const float* pp = partials + (parW << 16);
            float s = 0.0f;
            #pragma unroll
            for (int i = 0; i < 4; ++i) s += pp[((lane + (i << 6)) << 8) + bx];
            s += __shfl_xor(s, 32); s += __shfl_xor(s, 16); s += __shfl_xor(s, 8);
            s += __shfl_xor(s, 4);  s += __shfl_xor(s, 2);  s += __shfl_xor(s, 1);
            if (lane == 0) out[(bx << 9) + (it - 2)] = bouts_s + s;
        }

        // ---- phase A MFMA: gates1(t=it) += Whh1 . h1(it-1) ----------------
        if (it < Tsz) {
            const _Float16* bhB = HBUF(parR, 0, 0);
            const _Float16* blB = HBUF(parR, 0, 1);
            const int lo_off = (wv << 11) + (lane << 3);   // wv*4 chunks + lane
            #pragma unroll 4
            for (int bi = 0; bi < 16; ++bi) {
                const int bt = (bi + (wv << 1)) & 15;      // stagger waves
                const _Float16* ph = bhB + (bt << 14) + lo_off;
                const _Float16* pl = blB + (bt << 14) + lo_off;
                f32x4 a0 = {0, 0, 0, 0}, a1 = {0, 0, 0, 0};
                #pragma unroll
                for (int kt = 0; kt < 4; ++kt) {
                    const half8 bh = *(const half8*)(ph + (kt << 9));
                    const half8 bl = *(const half8*)(pl + (kt << 9));
                    a0 = MFMA(wAh[kt], bh, a0);
                    a1 = MFMA(wAh[kt], bl, a1);
                    a1 = MFMA(wAl[kt], bh, a1);
                }
                const int col = (bt << 4) + m;
                #pragma unroll
                for (int r = 0; r < 4; ++r)
                    atomicAdd(&gA[((quad << 2) + r) * GSTRIDE + col],
                              a0[r] + a1[r] * INV2048);
            }
        }

        // ---- phase B MFMA: gates2(t=it-1) += W2 . [h1(it-1); h2(it-2)] ----
        if (it >= 1) {
            const int l2 = (wv >= 4);
            const _Float16* bhB = l2 ? HBUF(parW, 1, 0) : HBUF(parR, 0, 0);
            const _Float16* blB = l2 ? HBUF(parW, 1, 1) : HBUF(parR, 0, 1);
            const int kcbase = (l2 ? (wv - 4) : wv) << 3;  // 8 chunks per wave
            const int lo_off = (kcbase << 9) + (lane << 3);
            #pragma unroll 2
            for (int bi = 0; bi < 16; ++bi) {
                const int bt = (bi + (wv << 1)) & 15;
                const _Float16* ph = bhB + (bt << 14) + lo_off;
                const _Float16* pl = blB + (bt << 14) + lo_off;
                f32x4 a0 = {0, 0, 0, 0}, a1 = {0, 0, 0, 0};
                #pragma unroll
                for (int kt = 0; kt < 8; ++kt) {
                    const half8 bh = *(const half8*)(ph + (kt << 9));
                    const half8 bl = *(const half8*)(pl + (kt << 9));
                    a0 = MFMA(wBh[kt], bh, a0);
                    a1 = MFMA(wBh[kt], bl, a1);
                    a1 = MFMA(wBl[kt], bh, a1);
                }
                const int col = (bt << 4) + m;
                #pragma unroll
                for (int r = 0; r < 4; ++r)
                    atomicAdd(&gB[((quad << 2) + r) * GSTRIDE + col],
                              a0[r] + a1[r] * INV2048);
            }
        }

        __syncthreads();   // all ds_adds done; epilogue reads gates

        // ---- epilogue: cell updates (thread tid == batch b) ---------------
        if (tid < 256) {
            const int b = tid;
            if (it < Tsz) {            // layer-1 cell for t=it -> h1(it) @parW
                half4 hhi, hlo;
                #pragma unroll
                for (int hf = 0; hf < 4; ++hf) {
                    const float gi = gA[(hf * 4 + 0) * GSTRIDE + b];
                    const float gf = gA[(hf * 4 + 1) * GSTRIDE + b];
                    const float gg = gA[(hf * 4 + 2) * GSTRIDE + b];
                    const float go = gA[(hf * 4 + 3) * GSTRIDE + b];
                    const float c  = sigm(gf) * c1r[hf] + sigm(gi) * tanh_f(gg);
                    c1r[hf] = c;
                    const float hn = sigm(go) * tanh_f(c);
                    hhi[hf] = (_Float16)hn;
                    hlo[hf] = (_Float16)((hn - (float)hhi[hf]) * 2048.0f);
                }
                *(half4*)(HBUF(parW, 0, 0) + wofs) = hhi;
                *(half4*)(HBUF(parW, 0, 1) + wofs) = hlo;
                if (it + 1 < Tsz) {    // re-init gA for t=it+1 (column-exclusive)
                    #pragma unroll
                    for (int p = 0; p < 16; ++p)
                        gA[p * GSTRIDE + b] = b1p[p] + xnext * wihp[p];
                }
            }
            if (it >= 1) {             // layer-2 cell for t=it-1 -> h2(it-1) @parR
                half4 hhi, hlo;
                float po = 0.0f;
                #pragma unroll
                for (int hf = 0; hf < 4; ++hf) {
                    const float gi = gB[(hf * 4 + 0) * GSTRIDE + b];
                    const float gf = gB[(hf * 4 + 1) * GSTRIDE + b];
                    const float gg = gB[(hf * 4 + 2) * GSTRIDE + b];
                    const float go = gB[(hf * 4 + 3) * GSTRIDE + b];
                    const float c  = sigm(gf) * c2r[hf] + sigm(gi) * tanh_f(gg);
                    c2r[hf] = c;
                    const float hn = sigm(go) * tanh_f(c);
                    hhi[hf] = (_Float16)hn;
                    hlo[hf] = (_Float16)((hn - (float)hhi[hf]) * 2048.0f);
                    po += hn * woutp[hf];
                }
                *(half4*)(HBUF(parR, 1, 0) + wofs) = hhi;
                *(half4*)(HBUF(parR, 1, 1) + wofs) = hlo;
                partials[(parR << 16) + (bx << 8) + b] = po;
                #pragma unroll
                for (int p = 0; p < 16; ++p)
                    gB[p * GSTRIDE + b] = b2p[p];
            }
        }

        grid_barrier(bar, 256u * (unsigned)(it + 1));
    }

    // tail: out column t=511 (partials written at it=512, parity 1)
    if (wv == 0) {
        const float* pp = partials + (1 << 16);
        float s = 0.0f;
        #pragma unroll
        for (int i = 0; i < 4; ++i) s += pp[((lane + (i << 6)) << 8) + bx];
        s += __shfl_xor(s, 32); s += __shfl_xor(s, 16); s += __shfl_xor(s, 8);
        s += __shfl_xor(s, 4);  s += __shfl_xor(s, 2);  s += __shfl_xor(s, 1);
        if (lane == 0) out[(bx << 9) + (Tsz - 1)] = bouts_s + s;
    }
    #undef HBUF
}

// ---------------------------------------------------------------------------
extern "C" void kernel_launch(void* const* d_in, const int* in_sizes, int n_in,
                              void* d_out, int out_size, void* d_ws, size_t ws_size,
                              hipStream_t stream)
{
    const float* x     = (const float*)d_in[0];
    const float* W_ih1 = (const float*)d_in[1];
    const float* W_hh1 = (const float*)d_in[2];
    const float* b_ih1 = (const float*)d_in[3];
    const float* b_hh1 = (const float*)d_in[4];
    const float* W_ih2 = (const float*)d_in[5];
    const float* W_hh2 = (const float*)d_in[6];
    const float* b_ih2 = (const float*)d_in[7];
    const float* b_hh2 = (const float*)d_in[8];
    const float* W_out = (const float*)d_in[9];
    const float* b_out = (const float*)d_in[10];
    float* out = (float*)d_out;
    char*  ws  = (char*)d_ws;

    void* args[] = {
        (void*)&x,
        (void*)&W_ih1, (void*)&W_hh1, (void*)&b_ih1, (void*)&b_hh1,
        (void*)&W_ih2, (void*)&W_hh2, (void*)&b_ih2, (void*)&b_hh2,
        (void*)&W_out, (void*)&b_out, (void*)&out, (void*)&ws,
    };
    hipLaunchCooperativeKernel((const void*)lstm_persist,
                               dim3(256), dim3(512), args, 0, stream);
}

// Round 5
// 53585.852 us; speedup vs baseline: 1.7122x; 1.1982x over previous
//
#include <hip/hip_runtime.h>
#include <hip/hip_cooperative_groups.h>
#include <math.h>

namespace cg = cooperative_groups;

#define Bsz 256
#define Tsz 512
#define GSTR 130    // gate-accum row stride (floats): 2-way LDS alias only (free)

using half8   = __attribute__((ext_vector_type(8))) _Float16;
using half2_t = __attribute__((ext_vector_type(2))) _Float16;
using f32x4   = __attribute__((ext_vector_type(4))) float;

#define MFMA(a, b, c) __builtin_amdgcn_mfma_f32_16x16x32_f16(a, b, c, 0, 0, 0)
#define INV2048 (1.0f / 2048.0f)

__device__ __forceinline__ float sigm(float v)   { return 1.0f / (1.0f + expf(-v)); }
__device__ __forceinline__ float tanh_f(float v) { float e = expf(2.0f * v); return 1.0f - 2.0f / (e + 1.0f); }

__device__ __forceinline__ void split8(const float* p, half8& hi, half8& lo) {
    float4 v0 = *(const float4*)p, v1 = *(const float4*)(p + 4);
    float vv[8] = {v0.x, v0.y, v0.z, v0.w, v1.x, v1.y, v1.z, v1.w};
    #pragma unroll
    for (int j = 0; j < 8; ++j) {
        hi[j] = (_Float16)vv[j];
        lo[j] = (_Float16)((vv[j] - (float)hi[j]) * 2048.0f);
    }
}

// Two-level grid barrier: 16 groups x 16 blocks. bar0[g] (ACQ_REL) chains each
// member's prior stores into the last-arriver, whose ACQ_REL add to bar1
// publishes them; spinners acquire-load bar1. Cuts 256-way same-line atomic
// serialization to 16-way + 16-way.
__device__ __forceinline__ void grid_barrier(unsigned* bar0, unsigned* bar1,
                                             int bx, unsigned target16) {
    __syncthreads();
    if (threadIdx.x == 0) {
        unsigned old = __hip_atomic_fetch_add(&bar0[(bx & 15) << 5], 1u,
                                              __ATOMIC_ACQ_REL, __HIP_MEMORY_SCOPE_AGENT);
        if ((old & 15u) == 15u)
            __hip_atomic_fetch_add(bar1, 1u, __ATOMIC_ACQ_REL, __HIP_MEMORY_SCOPE_AGENT);
        while (__hip_atomic_load(bar1, __ATOMIC_RELAXED, __HIP_MEMORY_SCOPE_AGENT) < target16)
            __builtin_amdgcn_s_sleep(2);
        (void)__hip_atomic_load(bar1, __ATOMIC_ACQUIRE, __HIP_MEMORY_SCOPE_AGENT);
    }
    __syncthreads();
}

// ---------------------------------------------------------------------------
// Persistent 2-layer LSTM, pipelined (phase A(t) || phase B(t-1), 1 barrier
// per step). 256 blocks x 512 threads. Block = row-group rg=bx>>1 (8 hidden
// units x 4 gates = 32 perm rows, BOTH layers) x batch-half BH=bx&1 (128 b).
// Weights VGPR-resident split-fp16 (hi + lo/2048): 192 VGPR/wave.
// h exchanged via global ws in MFMA-fragment-swizzled layout:
//   h[b][k] @ buf[(b>>4)<<14 | (k>>5)<<9 | ((b&15)|(((k>>3)&3)<<4))<<3 | (k&7)]
// so every B-frag load is one coalesced 1KB wave-load. Cell state in regs.
// ---------------------------------------------------------------------------
__global__ __launch_bounds__(512, 2) void lstm_persist(
    const float* __restrict__ x,
    const float* __restrict__ W_ih1, const float* __restrict__ W_hh1,
    const float* __restrict__ b_ih1, const float* __restrict__ b_hh1,
    const float* __restrict__ W_ih2, const float* __restrict__ W_hh2,
    const float* __restrict__ b_ih2, const float* __restrict__ b_hh2,
    const float* __restrict__ W_out, const float* __restrict__ b_out,
    float* __restrict__ out, char* __restrict__ ws)
{
    __shared__ float gA[32 * GSTR];   // layer-1 gate accum [perm row][b_loc]
    __shared__ float gB[32 * GSTR];   // layer-2 gate accum
    __shared__ float poArr[4 * GSTR]; // out-projection partial reduce
    __shared__ float b1p[32], b2p[32], wihp[32], woutp[8], bouts_s;

    cg::grid_group grid = cg::this_grid();

    const int tid  = threadIdx.x;
    const int lane = tid & 63;
    const int wv   = tid >> 6;        // 0..7: K-split index
    const int m    = lane & 15;
    const int quad = lane >> 4;
    const int bx   = blockIdx.x;
    const int rg   = bx >> 1;         // row-group 0..127
    const int BH   = bx & 1;          // batch half
    const int HO   = rg << 3;         // first hidden unit of this block

    // ---- workspace --------------------------------------------------------
    float*    xT       = (float*)ws;                                  // [512][256]
    _Float16* hswz     = (_Float16*)(ws + (512 << 10));               // 8 x 512KB
    float*    partials = (float*)(ws + (512 << 10) + (4 << 20));      // [2][256 b][128 rg]
    unsigned* bar0     = (unsigned*)(ws + (512 << 10) + (4 << 20) + (256 << 10));
    unsigned* bar1     = bar0 + 1024;

    #define HBUF(p, l, hl) (hswz + ((((p) << 2) | ((l) << 1) | (hl)) << 18))

    // ---- pre-loop init ----------------------------------------------------
    if (bx == 0) {
        if (tid < 16) bar0[tid << 5] = 0u;
        if (tid == 16) *bar1 = 0u;
    }
    if (tid < 32) {
        int row = ((tid & 3) << 10) + HO + (tid >> 2);   // perm row -> orig W row
        b1p[tid]  = b_ih1[row] + b_hh1[row];
        b2p[tid]  = b_ih2[row] + b_hh2[row];
        wihp[tid] = W_ih1[row];
        if (tid < 8) woutp[tid] = W_out[HO + tid];
        if (tid == 0) bouts_s = b_out[0];
    }
    {
        const int gidx = bx * 512 + tid;
        // zero parity-1 h region (h1(-1), h2(-1)): bytes [2MB, 4MB)
        *(float4*)((char*)hswz + (2u << 20) + (size_t)gidx * 16) = make_float4(0, 0, 0, 0);
        xT[gidx] = x[(gidx & 255) * Tsz + (gidx >> 8)];  // xT[t][b]
    }

    // ---- weight preload: 192 VGPR/wave of split-fp16 A-fragments ----------
    half8 wAh[2][4], wAl[2][4], wBh[2][8], wBl[2][8];
    #pragma unroll
    for (int mt = 0; mt < 2; ++mt) {
        const int pr = (mt << 4) + m;                    // perm row this lane holds
        const size_t rw = (size_t)(((pr & 3) << 10) + HO + (pr >> 2)) << 10;
        #pragma unroll
        for (int kt = 0; kt < 4; ++kt) {                 // layer 1, K-slice 128
            const int k = (wv << 7) + (kt << 5) + (quad << 3);
            split8(W_hh1 + rw + k, wAh[mt][kt], wAl[mt][kt]);
        }
        #pragma unroll
        for (int kt = 0; kt < 8; ++kt) {                 // layer 2, K-slice 256
            const int k = (wv << 8) + (kt << 5) + (quad << 3);
            const float* p = (k < 1024) ? (W_ih2 + rw + k) : (W_hh2 + rw + k - 1024);
            split8(p, wBh[mt][kt], wBl[mt][kt]);
        }
    }

    grid.sync();   // one-time heavy sync: xT, zeros, bar visible

    // gate accum init for it=0
    for (int idx = tid; idx < 4096; idx += 512) {
        const int p = idx >> 7, b = idx & 127;
        gA[p * GSTR + b] = b1p[p] + xT[(BH << 7) + b] * wihp[p];
        gB[p * GSTR + b] = b2p[p];
    }
    __syncthreads();

    float c1r[2] = {0, 0}, c2r[2] = {0, 0};
    const int b_loc = tid & 127, hp = tid >> 7;          // epilogue cell mapping
    const int bglob = (BH << 7) + b_loc;

    // ---- main loop: 513 iterations, one barrier each ----------------------
    for (int it = 0; it <= Tsz; ++it) {
        const int parW = it & 1;       // parity written for h1(it)
        const int parR = parW ^ 1;

        float xnext = 0.0f;
        if (it + 1 < Tsz) xnext = xT[((it + 1) << 8) + bglob];

        // out column t = it-2 (partials visible since last barrier)
        if (wv == 0 && it >= 2) {
            const float* pp = partials + (parW << 15) + (bx << 7);
            float s = pp[lane] + pp[lane + 64];
            s += __shfl_xor(s, 32); s += __shfl_xor(s, 16); s += __shfl_xor(s, 8);
            s += __shfl_xor(s, 4);  s += __shfl_xor(s, 2);  s += __shfl_xor(s, 1);
            if (lane == 0) out[(bx << 9) + (it - 2)] = bouts_s + s;
        }

        // ---- phase A: gates1(it) += Whh1 . h1(it-1) -----------------------
        if (it < Tsz) {
            const _Float16* bhB = HBUF(parR, 0, 0);
            const _Float16* blB = HBUF(parR, 0, 1);
            const int lo_off = (wv << 11) + (lane << 3);
            #pragma unroll 2
            for (int bi = 0; bi < 8; ++bi) {
                const int btl = (bi + wv) & 7;           // distinct slot per wave
                const _Float16* ph = bhB + (((BH << 3) + btl) << 14) + lo_off;
                const _Float16* pl = blB + (((BH << 3) + btl) << 14) + lo_off;
                f32x4 a0[2] = {(f32x4){0,0,0,0}, (f32x4){0,0,0,0}};
                f32x4 a1[2] = {(f32x4){0,0,0,0}, (f32x4){0,0,0,0}};
                #pragma unroll
                for (int kt = 0; kt < 4; ++kt) {
                    const half8 bh = *(const half8*)(ph + (kt << 9));
                    const half8 bl = *(const half8*)(pl + (kt << 9));
                    a0[0] = MFMA(wAh[0][kt], bh, a0[0]);
                    a1[0] = MFMA(wAh[0][kt], bl, a1[0]);
                    a1[0] = MFMA(wAl[0][kt], bh, a1[0]);
                    a0[1] = MFMA(wAh[1][kt], bh, a0[1]);
                    a1[1] = MFMA(wAh[1][kt], bl, a1[1]);
                    a1[1] = MFMA(wAl[1][kt], bh, a1[1]);
                }
                const int col = (btl << 4) + m;
                #pragma unroll
                for (int mt = 0; mt < 2; ++mt)
                    #pragma unroll
                    for (int r = 0; r < 4; ++r)
                        atomicAdd(&gA[((mt << 4) + (quad << 2) + r) * GSTR + col],
                                  a0[mt][r] + a1[mt][r] * INV2048);
            }
        }

        // ---- phase B: gates2(it-1) += W2 . [h1(it-1); h2(it-2)] -----------
        if (it >= 1) {
            const bool l2 = (wv >= 4);
            const _Float16* bhB = l2 ? HBUF(parW, 1, 0) : HBUF(parR, 0, 0);
            const _Float16* blB = l2 ? HBUF(parW, 1, 1) : HBUF(parR, 0, 1);
            const int lo_off = ((wv & 3) << 12) + (lane << 3);
            #pragma unroll 2
            for (int bi = 0; bi < 8; ++bi) {
                const int btl = (bi + wv) & 7;
                const _Float16* ph = bhB + (((BH << 3) + btl) << 14) + lo_off;
                const _Float16* pl = blB + (((BH << 3) + btl) << 14) + lo_off;
                f32x4 a0[2] = {(f32x4){0,0,0,0}, (f32x4){0,0,0,0}};
                f32x4 a1[2] = {(f32x4){0,0,0,0}, (f32x4){0,0,0,0}};
                #pragma unroll
                for (int kt = 0; kt < 8; ++kt) {
                    const half8 bh = *(const half8*)(ph + (kt << 9));
                    const half8 bl = *(const half8*)(pl + (kt << 9));
                    a0[0] = MFMA(wBh[0][kt], bh, a0[0]);
                    a1[0] = MFMA(wBh[0][kt], bl, a1[0]);
                    a1[0] = MFMA(wBl[0][kt], bh, a1[0]);
                    a0[1] = MFMA(wBh[1][kt], bh, a0[1]);
                    a1[1] = MFMA(wBh[1][kt], bl, a1[1]);
                    a1[1] = MFMA(wBl[1][kt], bh, a1[1]);
                }
                const int col = (btl << 4) + m;
                #pragma unroll
                for (int mt = 0; mt < 2; ++mt)
                    #pragma unroll
                    for (int r = 0; r < 4; ++r)
                        atomicAdd(&gB[((mt << 4) + (quad << 2) + r) * GSTR + col],
                                  a0[mt][r] + a1[mt][r] * INV2048);
            }
        }

        __syncthreads();   // gate accums complete

        // ---- epilogue: thread owns (b_loc, hid pair HO+2hp..+1), both layers
        if (it < Tsz) {                // layer-1 cell -> h1(it) @parW
            half2_t hhi, hlo;
            #pragma unroll
            for (int j = 0; j < 2; ++j) {
                const int p = (hp << 3) + (j << 2);
                const float gi = gA[(p + 0) * GSTR + b_loc];
                const float gf = gA[(p + 1) * GSTR + b_loc];
                const float gg = gA[(p + 2) * GSTR + b_loc];
                const float go = gA[(p + 3) * GSTR + b_loc];
                const float c  = sigm(gf) * c1r[j] + sigm(gi) * tanh_f(gg);
                c1r[j] = c;
                const float hn = sigm(go) * tanh_f(c);
                hhi[j] = (_Float16)hn;
                hlo[j] = (_Float16)((hn - (float)hhi[j]) * 2048.0f);
            }
            const int k0 = HO + (hp << 1);
            const int wofs = ((bglob >> 4) << 14) + ((k0 >> 5) << 9)
                           + (((bglob & 15) | (((k0 >> 3) & 3) << 4)) << 3) + (k0 & 7);
            *(half2_t*)(HBUF(parW, 0, 0) + wofs) = hhi;
            *(half2_t*)(HBUF(parW, 0, 1) + wofs) = hlo;
            if (it + 1 < Tsz) {        // re-init own gA rows (thread-exclusive)
                #pragma unroll
                for (int p = (hp << 3); p < (hp << 3) + 8; ++p)
                    gA[p * GSTR + b_loc] = b1p[p] + xnext * wihp[p];
            }
        }
        if (it >= 1) {                 // layer-2 cell for t=it-1 -> h2(it-1) @parR
            half2_t hhi, hlo;
            float po = 0.0f;
            #pragma unroll
            for (int j = 0; j < 2; ++j) {
                const int p = (hp << 3) + (j << 2);
                const float gi = gB[(p + 0) * GSTR + b_loc];
                const float gf = gB[(p + 1) * GSTR + b_loc];
                const float gg = gB[(p + 2) * GSTR + b_loc];
                const float go = gB[(p + 3) * GSTR + b_loc];
                const float c  = sigm(gf) * c2r[j] + sigm(gi) * tanh_f(gg);
                c2r[j] = c;
                const float hn = sigm(go) * tanh_f(c);
                hhi[j] = (_Float16)hn;
                hlo[j] = (_Float16)((hn - (float)hhi[j]) * 2048.0f);
                po += hn * woutp[(hp << 1) + j];
            }
            const int k0 = HO + (hp << 1);
            const int wofs = ((bglob >> 4) << 14) + ((k0 >> 5) << 9)
                           + (((bglob & 15) | (((k0 >> 3) & 3) << 4)) << 3) + (k0 & 7);
            *(half2_t*)(HBUF(parR, 1, 0) + wofs) = hhi;
            *(half2_t*)(HBUF(parR, 1, 1) + wofs) = hlo;
            poArr[hp * GSTR + b_loc] = po;
            #pragma unroll
            for (int p = (hp << 3); p < (hp << 3) + 8; ++p)
                gB[p * GSTR + b_loc] = b2p[p];
        }

        __syncthreads();
        if (it >= 1 && tid < 128) {    // finish out partial: sum over 4 hp
            const float s = poArr[tid] + poArr[GSTR + tid]
                          + poArr[2 * GSTR + tid] + poArr[3 * GSTR + tid];
            partials[((it & 1) ? 0 : (1 << 15)) + (((BH << 7) + tid) << 7) + rg] = s;
        }

        grid_barrier(bar0, bar1, bx, 16u * (unsigned)(it + 1));
    }

    // tail: out column t=511 (partials parity 1, written at it=512)
    if (wv == 0) {
        const float* pp = partials + (1 << 15) + (bx << 7);
        float s = pp[lane] + pp[lane + 64];
        s += __shfl_xor(s, 32); s += __shfl_xor(s, 16); s += __shfl_xor(s, 8);
        s += __shfl_xor(s, 4);  s += __shfl_xor(s, 2);  s += __shfl_xor(s, 1);
        if (lane == 0) out[(bx << 9) + (Tsz - 1)] = bouts_s + s;
    }
    #undef HBUF
}

// ---------------------------------------------------------------------------
extern "C" void kernel_launch(void* const* d_in, const int* in_sizes, int n_in,
                              void* d_out, int out_size, void* d_ws, size_t ws_size,
                              hipStream_t stream)
{
    const float* x     = (const float*)d_in[0];
    const float* W_ih1 = (const float*)d_in[1];
    const float* W_hh1 = (const float*)d_in[2];
    const float* b_ih1 = (const float*)d_in[3];
    const float* b_hh1 = (const float*)d_in[4];
    const float* W_ih2 = (const float*)d_in[5];
    const float* W_hh2 = (const float*)d_in[6];
    const float* b_ih2 = (const float*)d_in[7];
    const float* b_hh2 = (const float*)d_in[8];
    const float* W_out = (const float*)d_in[9];
    const float* b_out = (const float*)d_in[10];
    float* out = (float*)d_out;
    char*  ws  = (char*)d_ws;

    void* args[] = {
        (void*)&x,
        (void*)&W_ih1, (void*)&W_hh1, (void*)&b_ih1, (void*)&b_hh1,
        (void*)&W_ih2, (void*)&W_hh2, (void*)&b_ih2, (void*)&b_hh2,
        (void*)&W_out, (void*)&b_out, (void*)&out, (void*)&ws,
    };
    hipLaunchCooperativeKernel((const void*)lstm_persist,
                               dim3(256), dim3(512), args, 0, stream);
}

// Round 7
// 52323.712 us; speedup vs baseline: 1.7535x; 1.0241x over previous
//
#include <hip/hip_runtime.h>
#include <hip/hip_cooperative_groups.h>
#include <math.h>

namespace cg = cooperative_groups;

#define Bsz 256
#define Tsz 512
#define GSTR 258    // gate-accum row stride (floats): 2-way LDS alias only (free)

using half8 = __attribute__((ext_vector_type(8))) _Float16;
using half4 = __attribute__((ext_vector_type(4))) _Float16;
using f32x4 = __attribute__((ext_vector_type(4))) float;

#define MFMA_V(acc, a, b) (acc) = __builtin_amdgcn_mfma_f32_16x16x32_f16((a), (b), (acc), 0, 0, 0)
#define INV2048 (1.0f / 2048.0f)

__device__ __forceinline__ float sigm(float v)   { return 1.0f / (1.0f + expf(-v)); }
__device__ __forceinline__ float tanh_f(float v) { float e = expf(2.0f * v); return 1.0f - 2.0f / (e + 1.0f); }

__device__ __forceinline__ void split8(const float* p, half8& hi, half8& lo) {
    float4 v0 = *(const float4*)p, v1 = *(const float4*)(p + 4);
    float vv[8] = {v0.x, v0.y, v0.z, v0.w, v1.x, v1.y, v1.z, v1.w};
    #pragma unroll
    for (int j = 0; j < 8; ++j) {
        hi[j] = (_Float16)vv[j];
        lo[j] = (_Float16)((vv[j] - (float)hi[j]) * 2048.0f);
    }
}

// Two-level grid barrier (16 groups x 16 blocks) — R5-validated.
__device__ __forceinline__ void grid_barrier(unsigned* bar0, unsigned* bar1,
                                             int bx, unsigned target16) {
    __syncthreads();
    if (threadIdx.x == 0) {
        unsigned old = __hip_atomic_fetch_add(&bar0[(bx & 15) << 5], 1u,
                                              __ATOMIC_ACQ_REL, __HIP_MEMORY_SCOPE_AGENT);
        if ((old & 15u) == 15u)
            __hip_atomic_fetch_add(bar1, 1u, __ATOMIC_ACQ_REL, __HIP_MEMORY_SCOPE_AGENT);
        while (__hip_atomic_load(bar1, __ATOMIC_RELAXED, __HIP_MEMORY_SCOPE_AGENT) < target16)
            __builtin_amdgcn_s_sleep(2);
        (void)__hip_atomic_load(bar1, __ATOMIC_ACQUIRE, __HIP_MEMORY_SCOPE_AGENT);
    }
    __syncthreads();
}

// ---------------------------------------------------------------------------
// Persistent 2-layer LSTM, BLOCK-SPECIALIZED + pipelined, 1 barrier/step.
// 256 blocks x 512 threads (8 waves). Blocks 0..127: layer 1 (phase A, t=it).
// Blocks 128..255: layer 2 + out-projection (phase B, t=it-1). Each block owns
// 8 hidden units (32 perm gate-rows; perm p = hidoff*4+gate) x ALL 256 batch.
// Weights register-resident split-fp16 (hi + lo/2048):
//   L1-block: 2mt x 4kt x 2 = 16 half8 = 64 VGPR/wave (K-slice 128/wave)
//   L2-block: 2mt x 8kt x 2 = 32 half8 = 128 VGPR/wave (K-slice 256/wave)
// h exchanged via swizzled global layout (1KB coalesced wave-loads):
//   h[b][k] @ buf[(b>>4)<<14 | (k>>5)<<9 | ((b&15)|(((k>>3)&3)<<4))<<3 | (k&7)]
// Cell state in registers (thread = batch b x hidden-quad). Block bx reduces
// out[] for batch element bx (partials lag one iteration).
// ---------------------------------------------------------------------------
__global__ __launch_bounds__(512, 2) void lstm_persist(
    const float* __restrict__ x,
    const float* __restrict__ W_ih1, const float* __restrict__ W_hh1,
    const float* __restrict__ b_ih1, const float* __restrict__ b_hh1,
    const float* __restrict__ W_ih2, const float* __restrict__ W_hh2,
    const float* __restrict__ b_ih2, const float* __restrict__ b_hh2,
    const float* __restrict__ W_out, const float* __restrict__ b_out,
    float* __restrict__ out, char* __restrict__ ws)
{
    __shared__ float gAcc[32 * GSTR];   // gate accumulator [perm row][b]
    __shared__ float poArr[2 * GSTR];   // out-projection partials (L2 blocks)
    __shared__ float bp[32], wihp[32], woutp[8];
    __shared__ float bouts_s;

    cg::grid_group grid = cg::this_grid();

    const int tid  = threadIdx.x;
    const int lane = tid & 63;
    const int wv   = tid >> 6;        // 0..7: K-split index
    const int m    = lane & 15;
    const int quad = lane >> 4;
    const int bx   = blockIdx.x;
    const bool isL2 = (bx >= 128);
    const int rg   = isL2 ? (bx - 128) : bx;   // row-group 0..127 within layer
    const int HO   = rg << 3;                  // first hidden unit

    // ---- workspace --------------------------------------------------------
    float*    xT       = (float*)ws;                                  // [512][256]
    _Float16* hswz     = (_Float16*)(ws + (512 << 10));               // 8 x 512KB
    float*    partials = (float*)(ws + (512 << 10) + (4 << 20));      // [2][256 b][128 rg]
    unsigned* bar0     = (unsigned*)(ws + (512 << 10) + (4 << 20) + (256 << 10));
    unsigned* bar1     = bar0 + 1024;

    #define HBUF(p, l, hl) (hswz + ((((p) << 2) | ((l) << 1) | (hl)) << 18))

    // ---- pre-loop init ----------------------------------------------------
    if (bx == 0) {
        if (tid < 16) bar0[tid << 5] = 0u;
        if (tid == 16) *bar1 = 0u;
    }
    if (tid < 32) {
        const int row = ((tid & 3) << 10) + HO + (tid >> 2);  // perm row -> orig row
        if (!isL2) {
            bp[tid]   = b_ih1[row] + b_hh1[row];
            wihp[tid] = W_ih1[row];
        } else {
            bp[tid] = b_ih2[row] + b_hh2[row];
            if (tid < 8) woutp[tid] = W_out[HO + tid];
        }
        if (tid == 0) bouts_s = b_out[0];
    }
    {
        const int gidx = bx * 512 + tid;                 // 0..131071
        // zero parity-1 h region (h1(-1), h2(-1)): bytes [2MB, 4MB)
        *(float4*)((char*)hswz + (2u << 20) + (size_t)gidx * 16) = make_float4(0, 0, 0, 0);
        xT[gidx] = x[(gidx & 255) * Tsz + (gidx >> 8)];  // xT[t][b]
    }

    // ---- weight preload (spill-free by construction) ----------------------
    half8 wh[2][8], wl[2][8];           // L1 uses [..][0..3], L2 uses [..][0..7]
    const int nkt = isL2 ? 8 : 4;
    #pragma unroll
    for (int mt = 0; mt < 2; ++mt) {
        const int pr = (mt << 4) + m;
        const size_t rw = (size_t)(((pr & 3) << 10) + HO + (pr >> 2)) << 10;
        for (int kt = 0; kt < nkt; ++kt) {
            if (!isL2) {
                const int k = (wv << 7) + (kt << 5) + (quad << 3);
                split8(W_hh1 + rw + k, wh[mt][kt], wl[mt][kt]);
            } else {
                const int k = (wv << 8) + (kt << 5) + (quad << 3);
                const float* p = (k < 1024) ? (W_ih2 + rw + k)
                                            : (W_hh2 + rw + k - 1024);
                split8(p, wh[mt][kt], wl[mt][kt]);
            }
        }
    }

    grid.sync();   // one-time heavy sync: xT, zeros, bar visible

    // gate accumulator init for it=0
    for (int idx = tid; idx < 8192; idx += 512) {
        const int p = idx >> 8, b = idx & 255;
        gAcc[p * GSTR + b] = isL2 ? bp[p] : (bp[p] + xT[b] * wihp[p]);
    }
    __syncthreads();

    float cr[4] = {0, 0, 0, 0};
    const int b_ep = tid & 255, hg = tid >> 8;           // epilogue: batch, hidden-quad
    const int k0e  = HO + (hg << 2);
    const int wofs = ((b_ep >> 4) << 14) + ((k0e >> 5) << 9)
                   + (((b_ep & 15) | (((k0e >> 3) & 3) << 4)) << 3) + (k0e & 7);

    // ---- main loop: 513 iterations, one barrier each ----------------------
    for (int it = 0; it <= Tsz; ++it) {
        const int parW = it & 1;       // parity of h1(it) / h2(it)
        const int parR = parW ^ 1;     // parity of h1(it-1) / h2(it-2)... (see text)

        float xnext = 0.0f;
        if (!isL2 && it + 1 < Tsz) xnext = xT[((it + 1) << 8) + b_ep];

        // out column t = it-2 (partials written by L2 blocks last iteration)
        if (wv == 0 && it >= 2) {
            const float* pp = partials + (parW << 15) + (bx << 7);
            float s = pp[lane] + pp[lane + 64];
            s += __shfl_xor(s, 32); s += __shfl_xor(s, 16); s += __shfl_xor(s, 8);
            s += __shfl_xor(s, 4);  s += __shfl_xor(s, 2);  s += __shfl_xor(s, 1);
            if (lane == 0) out[(bx << 9) + (it - 2)] = bouts_s + s;
        }

        // ---- MFMA phase ---------------------------------------------------
        if (!isL2) {
            // gates1(it) += Whh1 . h1(it-1)   [K-slice 128 per wave]
            if (it < Tsz) {
                const _Float16* bhB = HBUF(parR, 0, 0);
                const _Float16* blB = HBUF(parR, 0, 1);
                const int lo_off = (wv << 11) + (lane << 3);
                #pragma unroll 2
                for (int bi = 0; bi < 16; ++bi) {
                    const int btl = (bi + (wv << 1)) & 15;
                    const _Float16* ph = bhB + (btl << 14) + lo_off;
                    const _Float16* pl = blB + (btl << 14) + lo_off;
                    f32x4 a0[2] = {(f32x4){0,0,0,0}, (f32x4){0,0,0,0}};
                    f32x4 a1[2] = {(f32x4){0,0,0,0}, (f32x4){0,0,0,0}};
                    half8 bh = *(const half8*)ph;
                    half8 bl = *(const half8*)pl;
                    #pragma unroll
                    for (int kt = 0; kt < 4; ++kt) {
                        half8 bhN, blN;
                        if (kt < 3) {
                            bhN = *(const half8*)(ph + ((kt + 1) << 9));
                            blN = *(const half8*)(pl + ((kt + 1) << 9));
                        }
                        MFMA_V(a0[0], wh[0][kt], bh);
                        MFMA_V(a1[0], wh[0][kt], bl);
                        MFMA_V(a1[0], wl[0][kt], bh);
                        MFMA_V(a0[1], wh[1][kt], bh);
                        MFMA_V(a1[1], wh[1][kt], bl);
                        MFMA_V(a1[1], wl[1][kt], bh);
                        bh = bhN; bl = blN;
                    }
                    const int col = (btl << 4) + m;
                    #pragma unroll
                    for (int mt = 0; mt < 2; ++mt)
                        #pragma unroll
                        for (int r = 0; r < 4; ++r)
                            atomicAdd(&gAcc[((mt << 4) + (quad << 2) + r) * GSTR + col],
                                      a0[mt][r] + a1[mt][r] * INV2048);
                }
            }
        } else {
            // gates2(it-1) += W2 . [h1(it-1); h2(it-2)]  [K-slice 256 per wave]
            if (it >= 1) {
                const bool hi2 = (wv >= 4);
                const _Float16* bhB = hi2 ? HBUF(parW, 1, 0) : HBUF(parR, 0, 0);
                const _Float16* blB = hi2 ? HBUF(parW, 1, 1) : HBUF(parR, 0, 1);
                const int lo_off = ((wv & 3) << 12) + (lane << 3);
                #pragma unroll 2
                for (int bi = 0; bi < 16; ++bi) {
                    const int btl = (bi + (wv << 1)) & 15;
                    const _Float16* ph = bhB + (btl << 14) + lo_off;
                    const _Float16* pl = blB + (btl << 14) + lo_off;
                    f32x4 a0[2] = {(f32x4){0,0,0,0}, (f32x4){0,0,0,0}};
                    f32x4 a1[2] = {(f32x4){0,0,0,0}, (f32x4){0,0,0,0}};
                    half8 bh = *(const half8*)ph;
                    half8 bl = *(const half8*)pl;
                    #pragma unroll
                    for (int kt = 0; kt < 8; ++kt) {
                        half8 bhN, blN;
                        if (kt < 7) {
                            bhN = *(const half8*)(ph + ((kt + 1) << 9));
                            blN = *(const half8*)(pl + ((kt + 1) << 9));
                        }
                        MFMA_V(a0[0], wh[0][kt], bh);
                        MFMA_V(a1[0], wh[0][kt], bl);
                        MFMA_V(a1[0], wl[0][kt], bh);
                        MFMA_V(a0[1], wh[1][kt], bh);
                        MFMA_V(a1[1], wh[1][kt], bl);
                        MFMA_V(a1[1], wl[1][kt], bh);
                        bh = bhN; bl = blN;
                    }
                    const int col = (btl << 4) + m;
                    #pragma unroll
                    for (int mt = 0; mt < 2; ++mt)
                        #pragma unroll
                        for (int r = 0; r < 4; ++r)
                            atomicAdd(&gAcc[((mt << 4) + (quad << 2) + r) * GSTR + col],
                                      a0[mt][r] + a1[mt][r] * INV2048);
                }
            }
        }

        __syncthreads();   // gate accums complete

        // ---- epilogue: thread owns (batch b_ep, hidden quad HO+4hg..+3) ---
        if (!isL2) {
            if (it < Tsz) {            // layer-1 cell -> h1(it) @parW
                half4 hhi, hlo;
                #pragma unroll
                for (int j = 0; j < 4; ++j) {
                    const int p = (hg << 4) + (j << 2);
                    const float gi = gAcc[(p + 0) * GSTR + b_ep];
                    const float gf = gAcc[(p + 1) * GSTR + b_ep];
                    const float gg = gAcc[(p + 2) * GSTR + b_ep];
                    const float go = gAcc[(p + 3) * GSTR + b_ep];
                    const float c  = sigm(gf) * cr[j] + sigm(gi) * tanh_f(gg);
                    cr[j] = c;
                    const float hn = sigm(go) * tanh_f(c);
                    hhi[j] = (_Float16)hn;
                    hlo[j] = (_Float16)((hn - (float)hhi[j]) * 2048.0f);
                }
                *(half4*)(HBUF(parW, 0, 0) + wofs) = hhi;
                *(half4*)(HBUF(parW, 0, 1) + wofs) = hlo;
                if (it + 1 < Tsz) {    // re-init own gAcc rows (thread-exclusive)
                    #pragma unroll
                    for (int p = (hg << 4); p < (hg << 4) + 16; ++p)
                        gAcc[p * GSTR + b_ep] = bp[p] + xnext * wihp[p];
                }
            }
        } else {
            if (it >= 1) {             // layer-2 cell for t=it-1 -> h2(it-1) @parR
                half4 hhi, hlo;
                float po = 0.0f;
                #pragma unroll
                for (int j = 0; j < 4; ++j) {
                    const int p = (hg << 4) + (j << 2);
                    const float gi = gAcc[(p + 0) * GSTR + b_ep];
                    const float gf = gAcc[(p + 1) * GSTR + b_ep];
                    const float gg = gAcc[(p + 2) * GSTR + b_ep];
                    const float go = gAcc[(p + 3) * GSTR + b_ep];
                    const float c  = sigm(gf) * cr[j] + sigm(gi) * tanh_f(gg);
                    cr[j] = c;
                    const float hn = sigm(go) * tanh_f(c);
                    hhi[j] = (_Float16)hn;
                    hlo[j] = (_Float16)((hn - (float)hhi[j]) * 2048.0f);
                    po += hn * woutp[(hg << 2) + j];
                }
                *(half4*)(HBUF(parR, 1, 0) + wofs) = hhi;
                *(half4*)(HBUF(parR, 1, 1) + wofs) = hlo;
                poArr[hg * GSTR + b_ep] = po;
                #pragma unroll
                for (int p = (hg << 4); p < (hg << 4) + 16; ++p)
                    gAcc[p * GSTR + b_ep] = bp[p];
            }
            __syncthreads();
            if (it >= 1 && tid < 256) {   // partials[parR][b][rg]
                const float s = poArr[tid] + poArr[GSTR + tid];
                partials[(parR << 15) + (tid << 7) + rg] = s;
            }
        }

        grid_barrier(bar0, bar1, bx, 16u * (unsigned)(it + 1));
    }

    // tail: out column t=511 (partials parity 1, written at it=512)
    if (wv == 0) {
        const float* pp = partials + (1 << 15) + (bx << 7);
        float s = pp[lane] + pp[lane + 64];
        s += __shfl_xor(s, 32); s += __shfl_xor(s, 16); s += __shfl_xor(s, 8);
        s += __shfl_xor(s, 4);  s += __shfl_xor(s, 2);  s += __shfl_xor(s, 1);
        if (lane == 0) out[(bx << 9) + (Tsz - 1)] = bouts_s + s;
    }
    #undef HBUF
}

// ---------------------------------------------------------------------------
extern "C" void kernel_launch(void* const* d_in, const int* in_sizes, int n_in,
                              void* d_out, int out_size, void* d_ws, size_t ws_size,
                              hipStream_t stream)
{
    const float* x     = (const float*)d_in[0];
    const float* W_ih1 = (const float*)d_in[1];
    const float* W_hh1 = (const float*)d_in[2];
    const float* b_ih1 = (const float*)d_in[3];
    const float* b_hh1 = (const float*)d_in[4];
    const float* W_ih2 = (const float*)d_in[5];
    const float* W_hh2 = (const float*)d_in[6];
    const float* b_ih2 = (const float*)d_in[7];
    const float* b_hh2 = (const float*)d_in[8];
    const float* W_out = (const float*)d_in[9];
    const float* b_out = (const float*)d_in[10];
    float* out = (float*)d_out;
    char*  ws  = (char*)d_ws;

    void* args[] = {
        (void*)&x,
        (void*)&W_ih1, (void*)&W_hh1, (void*)&b_ih1, (void*)&b_hh1,
        (void*)&W_ih2, (void*)&W_hh2, (void*)&b_ih2, (void*)&b_hh2,
        (void*)&W_out, (void*)&b_out, (void*)&out, (void*)&ws,
    };
    hipLaunchCooperativeKernel((const void*)lstm_persist,
                               dim3(256), dim3(512), args, 0, stream);
}

// Round 8
// 51741.479 us; speedup vs baseline: 1.7732x; 1.0113x over previous
//
#include <hip/hip_runtime.h>
#include <hip/hip_cooperative_groups.h>
#include <math.h>

namespace cg = cooperative_groups;

#define Bsz 256
#define Tsz 512
#define GSTR 258    // gate-accum row stride (floats): 2-way LDS alias only (free)

using half8 = __attribute__((ext_vector_type(8))) _Float16;
using half4 = __attribute__((ext_vector_type(4))) _Float16;
using f32x4 = __attribute__((ext_vector_type(4))) float;

#define MFMA_V(acc, a, b) (acc) = __builtin_amdgcn_mfma_f32_16x16x32_f16((a), (b), (acc), 0, 0, 0)
#define INV2048 (1.0f / 2048.0f)

__device__ __forceinline__ float sigm(float v)   { return 1.0f / (1.0f + expf(-v)); }
__device__ __forceinline__ float tanh_f(float v) { float e = expf(2.0f * v); return 1.0f - 2.0f / (e + 1.0f); }

__device__ __forceinline__ void split8(const float* p, half8& hi, half8& lo) {
    float4 v0 = *(const float4*)p, v1 = *(const float4*)(p + 4);
    float vv[8] = {v0.x, v0.y, v0.z, v0.w, v1.x, v1.y, v1.z, v1.w};
    #pragma unroll
    for (int j = 0; j < 8; ++j) {
        hi[j] = (_Float16)vv[j];
        lo[j] = (_Float16)((vv[j] - (float)hi[j]) * 2048.0f);
    }
}

// Two-level grid barrier (16 groups x 16 blocks) — R5-validated.
__device__ __forceinline__ void grid_barrier(unsigned* bar0, unsigned* bar1,
                                             int bx, unsigned target16) {
    __syncthreads();
    if (threadIdx.x == 0) {
        unsigned old = __hip_atomic_fetch_add(&bar0[(bx & 15) << 5], 1u,
                                              __ATOMIC_ACQ_REL, __HIP_MEMORY_SCOPE_AGENT);
        if ((old & 15u) == 15u)
            __hip_atomic_fetch_add(bar1, 1u, __ATOMIC_ACQ_REL, __HIP_MEMORY_SCOPE_AGENT);
        while (__hip_atomic_load(bar1, __ATOMIC_RELAXED, __HIP_MEMORY_SCOPE_AGENT) < target16)
            __builtin_amdgcn_s_sleep(2);
        (void)__hip_atomic_load(bar1, __ATOMIC_ACQUIRE, __HIP_MEMORY_SCOPE_AGENT);
    }
    __syncthreads();
}

// ---------------------------------------------------------------------------
// Persistent 2-layer LSTM, BLOCK-SPECIALIZED + pipelined, 1 barrier/step.
// Identical structure to R7 EXCEPT: the two specializations are fully
// duplicated code paths with compile-time-constant weight arrays and
// constant-bound unrolled preloads, so the weights provably live in
// registers (R7's runtime `nkt` bound demoted them to scratch ->
// 33 MB/step scratch reload traffic, FETCH_SIZE 16.9 GB).
// ---------------------------------------------------------------------------
__global__ __launch_bounds__(512, 2) void lstm_persist(
    const float* __restrict__ x,
    const float* __restrict__ W_ih1, const float* __restrict__ W_hh1,
    const float* __restrict__ b_ih1, const float* __restrict__ b_hh1,
    const float* __restrict__ W_ih2, const float* __restrict__ W_hh2,
    const float* __restrict__ b_ih2, const float* __restrict__ b_hh2,
    const float* __restrict__ W_out, const float* __restrict__ b_out,
    float* __restrict__ out, char* __restrict__ ws)
{
    __shared__ float gAcc[32 * GSTR];   // gate accumulator [perm row][b]
    __shared__ float poArr[2 * GSTR];   // out-projection partials (L2 blocks)
    __shared__ float bp[32], wihp[32], woutp[8];
    __shared__ float bouts_s;

    cg::grid_group grid = cg::this_grid();

    const int tid  = threadIdx.x;
    const int lane = tid & 63;
    const int wv   = tid >> 6;        // 0..7: K-split index
    const int m    = lane & 15;
    const int quad = lane >> 4;
    const int bx   = blockIdx.x;
    const bool isL2 = (bx >= 128);
    const int rg   = isL2 ? (bx - 128) : bx;   // row-group 0..127 within layer
    const int HO   = rg << 3;                  // first hidden unit

    // ---- workspace --------------------------------------------------------
    float*    xT       = (float*)ws;                                  // [512][256]
    _Float16* hswz     = (_Float16*)(ws + (512 << 10));               // 8 x 512KB
    float*    partials = (float*)(ws + (512 << 10) + (4 << 20));      // [2][256 b][128 rg]
    unsigned* bar0     = (unsigned*)(ws + (512 << 10) + (4 << 20) + (256 << 10));
    unsigned* bar1     = bar0 + 1024;

    #define HBUF(p, l, hl) (hswz + ((((p) << 2) | ((l) << 1) | (hl)) << 18))

    // ---- pre-loop init ----------------------------------------------------
    if (bx == 0) {
        if (tid < 16) bar0[tid << 5] = 0u;
        if (tid == 16) *bar1 = 0u;
    }
    if (tid < 32) {
        const int row = ((tid & 3) << 10) + HO + (tid >> 2);  // perm row -> orig row
        if (!isL2) {
            bp[tid]   = b_ih1[row] + b_hh1[row];
            wihp[tid] = W_ih1[row];
        } else {
            bp[tid] = b_ih2[row] + b_hh2[row];
            if (tid < 8) woutp[tid] = W_out[HO + tid];
        }
        if (tid == 0) bouts_s = b_out[0];
    }
    {
        const int gidx = bx * 512 + tid;                 // 0..131071
        // zero parity-1 h region (h1(-1), h2(-1)): bytes [2MB, 4MB)
        *(float4*)((char*)hswz + (2u << 20) + (size_t)gidx * 16) = make_float4(0, 0, 0, 0);
        xT[gidx] = x[(gidx & 255) * Tsz + (gidx >> 8)];  // xT[t][b]
    }

    grid.sync();   // one-time heavy sync: xT, zeros, bar visible

    const int b_ep = tid & 255, hg = tid >> 8;           // epilogue: batch, hidden-quad
    const int k0e  = HO + (hg << 2);
    const int wofs = ((b_ep >> 4) << 14) + ((k0e >> 5) << 9)
                   + (((b_ep & 15) | (((k0e >> 3) & 3) << 4)) << 3) + (k0e & 7);

    if (!isL2) {
        // ==================== LAYER-1 BLOCKS ===============================
        // weights: 2mt x 4kt x (hi,lo) = 16 half8 = 64 VGPR/wave, K-slice 128
        half8 wh[2][4], wl[2][4];
        #pragma unroll
        for (int mt = 0; mt < 2; ++mt) {
            const int pr = (mt << 4) + m;
            const size_t rw = (size_t)(((pr & 3) << 10) + HO + (pr >> 2)) << 10;
            #pragma unroll
            for (int kt = 0; kt < 4; ++kt) {
                const int k = (wv << 7) + (kt << 5) + (quad << 3);
                split8(W_hh1 + rw + k, wh[mt][kt], wl[mt][kt]);
            }
        }
        for (int idx = tid; idx < 8192; idx += 512) {    // gAcc init for it=0
            const int p = idx >> 8, b = idx & 255;
            gAcc[p * GSTR + b] = bp[p] + xT[b] * wihp[p];
        }
        __syncthreads();
        float cr[4] = {0, 0, 0, 0};

        for (int it = 0; it <= Tsz; ++it) {
            const int parW = it & 1;
            const int parR = parW ^ 1;

            float xnext = 0.0f;
            if (it + 1 < Tsz) xnext = xT[((it + 1) << 8) + b_ep];

            if (wv == 0 && it >= 2) {                    // out column t=it-2
                const float* pp = partials + (parW << 15) + (bx << 7);
                float s = pp[lane] + pp[lane + 64];
                s += __shfl_xor(s, 32); s += __shfl_xor(s, 16); s += __shfl_xor(s, 8);
                s += __shfl_xor(s, 4);  s += __shfl_xor(s, 2);  s += __shfl_xor(s, 1);
                if (lane == 0) out[(bx << 9) + (it - 2)] = bouts_s + s;
            }

            // gates1(it) += Whh1 . h1(it-1)
            if (it < Tsz) {
                const _Float16* bhB = HBUF(parR, 0, 0);
                const _Float16* blB = HBUF(parR, 0, 1);
                const int lo_off = (wv << 11) + (lane << 3);
                #pragma unroll 2
                for (int bi = 0; bi < 16; ++bi) {
                    const int btl = (bi + (wv << 1)) & 15;
                    const _Float16* ph = bhB + (btl << 14) + lo_off;
                    const _Float16* pl = blB + (btl << 14) + lo_off;
                    f32x4 a0[2] = {(f32x4){0,0,0,0}, (f32x4){0,0,0,0}};
                    f32x4 a1[2] = {(f32x4){0,0,0,0}, (f32x4){0,0,0,0}};
                    half8 bh = *(const half8*)ph;
                    half8 bl = *(const half8*)pl;
                    #pragma unroll
                    for (int kt = 0; kt < 4; ++kt) {
                        half8 bhN, blN;
                        if (kt < 3) {
                            bhN = *(const half8*)(ph + ((kt + 1) << 9));
                            blN = *(const half8*)(pl + ((kt + 1) << 9));
                        }
                        MFMA_V(a0[0], wh[0][kt], bh);
                        MFMA_V(a1[0], wh[0][kt], bl);
                        MFMA_V(a1[0], wl[0][kt], bh);
                        MFMA_V(a0[1], wh[1][kt], bh);
                        MFMA_V(a1[1], wh[1][kt], bl);
                        MFMA_V(a1[1], wl[1][kt], bh);
                        bh = bhN; bl = blN;
                    }
                    const int col = (btl << 4) + m;
                    #pragma unroll
                    for (int mt = 0; mt < 2; ++mt)
                        #pragma unroll
                        for (int r = 0; r < 4; ++r)
                            atomicAdd(&gAcc[((mt << 4) + (quad << 2) + r) * GSTR + col],
                                      a0[mt][r] + a1[mt][r] * INV2048);
                }
            }

            __syncthreads();

            if (it < Tsz) {            // layer-1 cell -> h1(it) @parW
                half4 hhi, hlo;
                #pragma unroll
                for (int j = 0; j < 4; ++j) {
                    const int p = (hg << 4) + (j << 2);
                    const float gi = gAcc[(p + 0) * GSTR + b_ep];
                    const float gf = gAcc[(p + 1) * GSTR + b_ep];
                    const float gg = gAcc[(p + 2) * GSTR + b_ep];
                    const float go = gAcc[(p + 3) * GSTR + b_ep];
                    const float c  = sigm(gf) * cr[j] + sigm(gi) * tanh_f(gg);
                    cr[j] = c;
                    const float hn = sigm(go) * tanh_f(c);
                    hhi[j] = (_Float16)hn;
                    hlo[j] = (_Float16)((hn - (float)hhi[j]) * 2048.0f);
                }
                *(half4*)(HBUF(parW, 0, 0) + wofs) = hhi;
                *(half4*)(HBUF(parW, 0, 1) + wofs) = hlo;
                if (it + 1 < Tsz) {
                    #pragma unroll
                    for (int p = (hg << 4); p < (hg << 4) + 16; ++p)
                        gAcc[p * GSTR + b_ep] = bp[p] + xnext * wihp[p];
                }
            }

            grid_barrier(bar0, bar1, bx, 16u * (unsigned)(it + 1));
        }
    } else {
        // ==================== LAYER-2 BLOCKS ===============================
        // weights: 2mt x 8kt x (hi,lo) = 32 half8 = 128 VGPR/wave, K-slice 256
        half8 wh[2][8], wl[2][8];
        #pragma unroll
        for (int mt = 0; mt < 2; ++mt) {
            const int pr = (mt << 4) + m;
            const size_t rw = (size_t)(((pr & 3) << 10) + HO + (pr >> 2)) << 10;
            #pragma unroll
            for (int kt = 0; kt < 8; ++kt) {
                const int k = (wv << 8) + (kt << 5) + (quad << 3);
                const float* p = (k < 1024) ? (W_ih2 + rw + k)
                                            : (W_hh2 + rw + k - 1024);
                split8(p, wh[mt][kt], wl[mt][kt]);
            }
        }
        for (int idx = tid; idx < 8192; idx += 512) {    // gAcc init
            const int p = idx >> 8, b = idx & 255;
            gAcc[p * GSTR + b] = bp[p];
        }
        __syncthreads();
        float cr[4] = {0, 0, 0, 0};

        for (int it = 0; it <= Tsz; ++it) {
            const int parW = it & 1;
            const int parR = parW ^ 1;

            if (wv == 0 && it >= 2) {                    // out column t=it-2
                const float* pp = partials + (parW << 15) + (bx << 7);
                float s = pp[lane] + pp[lane + 64];
                s += __shfl_xor(s, 32); s += __shfl_xor(s, 16); s += __shfl_xor(s, 8);
                s += __shfl_xor(s, 4);  s += __shfl_xor(s, 2);  s += __shfl_xor(s, 1);
                if (lane == 0) out[(bx << 9) + (it - 2)] = bouts_s + s;
            }

            // gates2(it-1) += W2 . [h1(it-1); h2(it-2)]
            if (it >= 1) {
                const bool hi2 = (wv >= 4);
                const _Float16* bhB = hi2 ? HBUF(parW, 1, 0) : HBUF(parR, 0, 0);
                const _Float16* blB = hi2 ? HBUF(parW, 1, 1) : HBUF(parR, 0, 1);
                const int lo_off = ((wv & 3) << 12) + (lane << 3);
                #pragma unroll 2
                for (int bi = 0; bi < 16; ++bi) {
                    const int btl = (bi + (wv << 1)) & 15;
                    const _Float16* ph = bhB + (btl << 14) + lo_off;
                    const _Float16* pl = blB + (btl << 14) + lo_off;
                    f32x4 a0[2] = {(f32x4){0,0,0,0}, (f32x4){0,0,0,0}};
                    f32x4 a1[2] = {(f32x4){0,0,0,0}, (f32x4){0,0,0,0}};
                    half8 bh = *(const half8*)ph;
                    half8 bl = *(const half8*)pl;
                    #pragma unroll
                    for (int kt = 0; kt < 8; ++kt) {
                        half8 bhN, blN;
                        if (kt < 7) {
                            bhN = *(const half8*)(ph + ((kt + 1) << 9));
                            blN = *(const half8*)(pl + ((kt + 1) << 9));
                        }
                        MFMA_V(a0[0], wh[0][kt], bh);
                        MFMA_V(a1[0], wh[0][kt], bl);
                        MFMA_V(a1[0], wl[0][kt], bh);
                        MFMA_V(a0[1], wh[1][kt], bh);
                        MFMA_V(a1[1], wh[1][kt], bl);
                        MFMA_V(a1[1], wl[1][kt], bh);
                        bh = bhN; bl = blN;
                    }
                    const int col = (btl << 4) + m;
                    #pragma unroll
                    for (int mt = 0; mt < 2; ++mt)
                        #pragma unroll
                        for (int r = 0; r < 4; ++r)
                            atomicAdd(&gAcc[((mt << 4) + (quad << 2) + r) * GSTR + col],
                                      a0[mt][r] + a1[mt][r] * INV2048);
                }
            }

            __syncthreads();

            if (it >= 1) {             // layer-2 cell for t=it-1 -> h2(it-1) @parR
                half4 hhi, hlo;
                float po = 0.0f;
                #pragma unroll
                for (int j = 0; j < 4; ++j) {
                    const int p = (hg << 4) + (j << 2);
                    const float gi = gAcc[(p + 0) * GSTR + b_ep];
                    const float gf = gAcc[(p + 1) * GSTR + b_ep];
                    const float gg = gAcc[(p + 2) * GSTR + b_ep];
                    const float go = gAcc[(p + 3) * GSTR + b_ep];
                    const float c  = sigm(gf) * cr[j] + sigm(gi) * tanh_f(gg);
                    cr[j] = c;
                    const float hn = sigm(go) * tanh_f(c);
                    hhi[j] = (_Float16)hn;
                    hlo[j] = (_Float16)((hn - (float)hhi[j]) * 2048.0f);
                    po += hn * woutp[(hg << 2) + j];
                }
                *(half4*)(HBUF(parR, 1, 0) + wofs) = hhi;
                *(half4*)(HBUF(parR, 1, 1) + wofs) = hlo;
                poArr[hg * GSTR + b_ep] = po;
                #pragma unroll
                for (int p = (hg << 4); p < (hg << 4) + 16; ++p)
                    gAcc[p * GSTR + b_ep] = bp[p];
            }
            __syncthreads();
            if (it >= 1 && tid < 256) {   // partials[parR][b][rg]
                const float s = poArr[tid] + poArr[GSTR + tid];
                partials[(parR << 15) + (tid << 7) + rg] = s;
            }

            grid_barrier(bar0, bar1, bx, 16u * (unsigned)(it + 1));
        }
    }

    // tail: out column t=511 (partials parity 1, written at it=512)
    if (wv == 0) {
        const float* pp = partials + (1 << 15) + (bx << 7);
        float s = pp[lane] + pp[lane + 64];
        s += __shfl_xor(s, 32); s += __shfl_xor(s, 16); s += __shfl_xor(s, 8);
        s += __shfl_xor(s, 4);  s += __shfl_xor(s, 2);  s += __shfl_xor(s, 1);
        if (lane == 0) out[(bx << 9) + (Tsz - 1)] = bouts_s + s;
    }
    #undef HBUF
}

// ---------------------------------------------------------------------------
extern "C" void kernel_launch(void* const* d_in, const int* in_sizes, int n_in,
                              void* d_out, int out_size, void* d_ws, size_t ws_size,
                              hipStream_t stream)
{
    const float* x     = (const float*)d_in[0];
    const float* W_ih1 = (const float*)d_in[1];
    const float* W_hh1 = (const float*)d_in[2];
    const float* b_ih1 = (const float*)d_in[3];
    const float* b_hh1 = (const float*)d_in[4];
    const float* W_ih2 = (const float*)d_in[5];
    const float* W_hh2 = (const float*)d_in[6];
    const float* b_ih2 = (const float*)d_in[7];
    const float* b_hh2 = (const float*)d_in[8];
    const float* W_out = (const float*)d_in[9];
    const float* b_out = (const float*)d_in[10];
    float* out = (float*)d_out;
    char*  ws  = (char*)d_ws;

    void* args[] = {
        (void*)&x,
        (void*)&W_ih1, (void*)&W_hh1, (void*)&b_ih1, (void*)&b_hh1,
        (void*)&W_ih2, (void*)&W_hh2, (void*)&b_ih2, (void*)&b_hh2,
        (void*)&W_out, (void*)&b_out, (void*)&out, (void*)&ws,
    };
    hipLaunchCooperativeKernel((const void*)lstm_persist,
                               dim3(256), dim3(512), args, 0, stream);
}

// Round 9
// 47778.391 us; speedup vs baseline: 1.9203x; 1.0829x over previous
//
#include <hip/hip_runtime.h>
#include <hip/hip_cooperative_groups.h>
#include <math.h>

namespace cg = cooperative_groups;

#define Bsz 256
#define Tsz 512
#define GSTR 258    // gate-accum row stride (floats): 2-way LDS alias only (free)

using half8 = __attribute__((ext_vector_type(8))) _Float16;
using half4 = __attribute__((ext_vector_type(4))) _Float16;
using f32x4 = __attribute__((ext_vector_type(4))) float;

#define MFMA_V(acc, a, b) (acc) = __builtin_amdgcn_mfma_f32_16x16x32_f16((a), (b), (acc), 0, 0, 0)
#define INV2048 (1.0f / 2048.0f)

__device__ __forceinline__ float sigm(float v)   { return 1.0f / (1.0f + expf(-v)); }
__device__ __forceinline__ float tanh_f(float v) { float e = expf(2.0f * v); return 1.0f - 2.0f / (e + 1.0f); }

__device__ __forceinline__ void split8(const float* p, half8& hi, half8& lo) {
    float4 v0 = *(const float4*)p, v1 = *(const float4*)(p + 4);
    float vv[8] = {v0.x, v0.y, v0.z, v0.w, v1.x, v1.y, v1.z, v1.w};
    #pragma unroll
    for (int j = 0; j < 8; ++j) {
        hi[j] = (_Float16)vv[j];
        lo[j] = (_Float16)((vv[j] - (float)hi[j]) * 2048.0f);
    }
}

// ---------------------------------------------------------------------------
// Leader-based step barrier. Arrivals are RELAXED (no cache maintenance).
// One elected leader per *physical* XCD (by HW_REG_XCC_ID) performs the only
// L2 writeback+invalidate (via a compiler-generated agent-scope ACQ_REL RMW
// on an XCD-private line), then signals phase2. Every CU then invalidates its
// own L1 (buffer_inv sc0). Data stores are guaranteed in L2 before arrival by
// __syncthreads' implicit vmcnt(0) drain.
// ---------------------------------------------------------------------------
__device__ __forceinline__ void step_barrier(unsigned* bar0, unsigned* bar1,
                                             unsigned* phase2, unsigned* dummyv,
                                             int bx, int isLead, unsigned xcc,
                                             unsigned nLead, unsigned it1) {
    __syncthreads();   // all waves' stores drained to L2 (vmcnt 0)
    if (threadIdx.x == 0) {
        unsigned old = __hip_atomic_fetch_add(&bar0[(bx & 15) << 5], 1u,
                                              __ATOMIC_RELAXED, __HIP_MEMORY_SCOPE_AGENT);
        if ((old & 15u) == 15u)
            __hip_atomic_fetch_add(bar1, 1u, __ATOMIC_RELAXED, __HIP_MEMORY_SCOPE_AGENT);
        if (isLead) {
            while (__hip_atomic_load(bar1, __ATOMIC_RELAXED, __HIP_MEMORY_SCOPE_AGENT) < 16u * it1)
                __builtin_amdgcn_s_sleep(1);
            // the ONE wbL2+invL2 for this XCD
            __hip_atomic_fetch_add(&dummyv[xcc << 5], 1u,
                                   __ATOMIC_ACQ_REL, __HIP_MEMORY_SCOPE_AGENT);
            __hip_atomic_fetch_add(phase2, 1u,
                                   __ATOMIC_RELAXED, __HIP_MEMORY_SCOPE_AGENT);
        }
        while (__hip_atomic_load(phase2, __ATOMIC_RELAXED, __HIP_MEMORY_SCOPE_AGENT) < nLead * it1)
            __builtin_amdgcn_s_sleep(1);
        asm volatile("buffer_inv sc0" ::: "memory");   // own-CU L1 invalidate
    }
    __syncthreads();
}

// ---------------------------------------------------------------------------
// Persistent 2-layer LSTM, BLOCK-SPECIALIZED + pipelined, 1 barrier/step.
// Structure = R8 except: (a) __launch_bounds__(512,1) -> 256-VGPR budget so
// the weight fragments are truly register-resident (R4-R8 were capped at 128
// and silently spilled); (b) leader-based barrier maintenance (above).
// ---------------------------------------------------------------------------
__global__ __launch_bounds__(512, 1) void lstm_persist(
    const float* __restrict__ x,
    const float* __restrict__ W_ih1, const float* __restrict__ W_hh1,
    const float* __restrict__ b_ih1, const float* __restrict__ b_hh1,
    const float* __restrict__ W_ih2, const float* __restrict__ W_hh2,
    const float* __restrict__ b_ih2, const float* __restrict__ b_hh2,
    const float* __restrict__ W_out, const float* __restrict__ b_out,
    float* __restrict__ out, char* __restrict__ ws)
{
    __shared__ float gAcc[32 * GSTR];   // gate accumulator [perm row][b]
    __shared__ float poArr[2 * GSTR];   // out-projection partials (L2 blocks)
    __shared__ float bp[32], wihp[32], woutp[8];
    __shared__ float bouts_s;
    __shared__ unsigned isLead_s, xcc_s, nLead_s;

    cg::grid_group grid = cg::this_grid();

    const int tid  = threadIdx.x;
    const int lane = tid & 63;
    const int wv   = tid >> 6;        // 0..7: K-split index
    const int m    = lane & 15;
    const int quad = lane >> 4;
    const int bx   = blockIdx.x;
    const bool isL2 = (bx >= 128);
    const int rg   = isL2 ? (bx - 128) : bx;   // row-group 0..127 within layer
    const int HO   = rg << 3;                  // first hidden unit

    // ---- workspace --------------------------------------------------------
    float*    xT       = (float*)ws;                                  // [512][256]
    _Float16* hswz     = (_Float16*)(ws + (512 << 10));               // 8 x 512KB
    float*    partials = (float*)(ws + (512 << 10) + (4 << 20));      // [2][256 b][128 rg]
    unsigned* bar0     = (unsigned*)(ws + (512 << 10) + (4 << 20) + (256 << 10));
    unsigned* bar1     = bar0 + 1024;
    unsigned* phase2   = bar0 + 1056;
    unsigned* nLeadCt  = bar0 + 1057;
    unsigned* claimA   = bar0 + 1088;   // + (xcc<<5)
    unsigned* dummyv   = bar0 + 1536;   // + (xcc<<5)

    #define HBUF(p, l, hl) (hswz + ((((p) << 2) | ((l) << 1) | (hl)) << 18))

    // ---- pre-loop init ----------------------------------------------------
    if (bx == 0)
        for (int i = tid; i < 2048; i += 512) bar0[i] = 0u;   // all counters
    if (tid < 32) {
        const int row = ((tid & 3) << 10) + HO + (tid >> 2);  // perm row -> orig row
        if (!isL2) {
            bp[tid]   = b_ih1[row] + b_hh1[row];
            wihp[tid] = W_ih1[row];
        } else {
            bp[tid] = b_ih2[row] + b_hh2[row];
            if (tid < 8) woutp[tid] = W_out[HO + tid];
        }
        if (tid == 0) bouts_s = b_out[0];
    }
    {
        const int gidx = bx * 512 + tid;                 // 0..131071
        // zero parity-1 h region (h1(-1), h2(-1)): bytes [2MB, 4MB)
        *(float4*)((char*)hswz + (2u << 20) + (size_t)gidx * 16) = make_float4(0, 0, 0, 0);
        xT[gidx] = x[(gidx & 255) * Tsz + (gidx >> 8)];  // xT[t][b]
    }

    grid.sync();   // heavy sync #1: xT, zeros, counters visible

    // ---- leader election by PHYSICAL XCD id -------------------------------
    if (tid == 0) {
        unsigned xcc;
        asm volatile("s_getreg_b32 %0, hwreg(HW_REG_XCC_ID)" : "=s"(xcc));
        xcc &= 7u;
        xcc_s = xcc;
        unsigned old = __hip_atomic_fetch_add(&claimA[xcc << 5], 1u,
                                              __ATOMIC_RELAXED, __HIP_MEMORY_SCOPE_AGENT);
        isLead_s = (old == 0u);
        if (old == 0u)
            __hip_atomic_fetch_add(nLeadCt, 1u,
                                   __ATOMIC_RELAXED, __HIP_MEMORY_SCOPE_AGENT);
    }
    grid.sync();   // heavy sync #2: all elections final
    if (tid == 0)
        nLead_s = __hip_atomic_load(nLeadCt, __ATOMIC_RELAXED, __HIP_MEMORY_SCOPE_AGENT);
    __syncthreads();
    const int      isLead = (int)isLead_s;
    const unsigned xcc    = xcc_s;
    const unsigned nLead  = nLead_s;

    const int b_ep = tid & 255, hg = tid >> 8;           // epilogue: batch, hidden-quad
    const int k0e  = HO + (hg << 2);
    const int wofs = ((b_ep >> 4) << 14) + ((k0e >> 5) << 9)
                   + (((b_ep & 15) | (((k0e >> 3) & 3) << 4)) << 3) + (k0e & 7);

    if (!isL2) {
        // ==================== LAYER-1 BLOCKS ===============================
        half8 wh[2][4], wl[2][4];     // 64 VGPR/wave, K-slice 128
        #pragma unroll
        for (int mt = 0; mt < 2; ++mt) {
            const int pr = (mt << 4) + m;
            const size_t rw = (size_t)(((pr & 3) << 10) + HO + (pr >> 2)) << 10;
            #pragma unroll
            for (int kt = 0; kt < 4; ++kt) {
                const int k = (wv << 7) + (kt << 5) + (quad << 3);
                split8(W_hh1 + rw + k, wh[mt][kt], wl[mt][kt]);
            }
        }
        for (int idx = tid; idx < 8192; idx += 512) {    // gAcc init for it=0
            const int p = idx >> 8, b = idx & 255;
            gAcc[p * GSTR + b] = bp[p] + xT[b] * wihp[p];
        }
        __syncthreads();
        float cr[4] = {0, 0, 0, 0};

        for (int it = 0; it <= Tsz; ++it) {
            const int parW = it & 1;
            const int parR = parW ^ 1;

            float xnext = 0.0f;
            if (it + 1 < Tsz) xnext = xT[((it + 1) << 8) + b_ep];

            if (wv == 0 && it >= 2) {                    // out column t=it-2
                const float* pp = partials + (parW << 15) + (bx << 7);
                float s = pp[lane] + pp[lane + 64];
                s += __shfl_xor(s, 32); s += __shfl_xor(s, 16); s += __shfl_xor(s, 8);
                s += __shfl_xor(s, 4);  s += __shfl_xor(s, 2);  s += __shfl_xor(s, 1);
                if (lane == 0) out[(bx << 9) + (it - 2)] = bouts_s + s;
            }

            // gates1(it) += Whh1 . h1(it-1)
            if (it < Tsz) {
                const _Float16* bhB = HBUF(parR, 0, 0);
                const _Float16* blB = HBUF(parR, 0, 1);
                const int lo_off = (wv << 11) + (lane << 3);
                #pragma unroll 2
                for (int bi = 0; bi < 16; ++bi) {
                    const int btl = (bi + (wv << 1)) & 15;
                    const _Float16* ph = bhB + (btl << 14) + lo_off;
                    const _Float16* pl = blB + (btl << 14) + lo_off;
                    f32x4 a0[2] = {(f32x4){0,0,0,0}, (f32x4){0,0,0,0}};
                    f32x4 a1[2] = {(f32x4){0,0,0,0}, (f32x4){0,0,0,0}};
                    half8 bh = *(const half8*)ph;
                    half8 bl = *(const half8*)pl;
                    #pragma unroll
                    for (int kt = 0; kt < 4; ++kt) {
                        half8 bhN, blN;
                        if (kt < 3) {
                            bhN = *(const half8*)(ph + ((kt + 1) << 9));
                            blN = *(const half8*)(pl + ((kt + 1) << 9));
                        }
                        MFMA_V(a0[0], wh[0][kt], bh);
                        MFMA_V(a1[0], wh[0][kt], bl);
                        MFMA_V(a1[0], wl[0][kt], bh);
                        MFMA_V(a0[1], wh[1][kt], bh);
                        MFMA_V(a1[1], wh[1][kt], bl);
                        MFMA_V(a1[1], wl[1][kt], bh);
                        bh = bhN; bl = blN;
                    }
                    const int col = (btl << 4) + m;
                    #pragma unroll
                    for (int mt = 0; mt < 2; ++mt)
                        #pragma unroll
                        for (int r = 0; r < 4; ++r)
                            atomicAdd(&gAcc[((mt << 4) + (quad << 2) + r) * GSTR + col],
                                      a0[mt][r] + a1[mt][r] * INV2048);
                }
            }

            __syncthreads();

            if (it < Tsz) {            // layer-1 cell -> h1(it) @parW
                half4 hhi, hlo;
                #pragma unroll
                for (int j = 0; j < 4; ++j) {
                    const int p = (hg << 4) + (j << 2);
                    const float gi = gAcc[(p + 0) * GSTR + b_ep];
                    const float gf = gAcc[(p + 1) * GSTR + b_ep];
                    const float gg = gAcc[(p + 2) * GSTR + b_ep];
                    const float go = gAcc[(p + 3) * GSTR + b_ep];
                    const float c  = sigm(gf) * cr[j] + sigm(gi) * tanh_f(gg);
                    cr[j] = c;
                    const float hn = sigm(go) * tanh_f(c);
                    hhi[j] = (_Float16)hn;
                    hlo[j] = (_Float16)((hn - (float)hhi[j]) * 2048.0f);
                }
                *(half4*)(HBUF(parW, 0, 0) + wofs) = hhi;
                *(half4*)(HBUF(parW, 0, 1) + wofs) = hlo;
                if (it + 1 < Tsz) {
                    #pragma unroll
                    for (int p = (hg << 4); p < (hg << 4) + 16; ++p)
                        gAcc[p * GSTR + b_ep] = bp[p] + xnext * wihp[p];
                }
            }

            step_barrier(bar0, bar1, phase2, dummyv, bx, isLead, xcc, nLead,
                         (unsigned)(it + 1));
        }
    } else {
        // ==================== LAYER-2 BLOCKS ===============================
        half8 wh[2][8], wl[2][8];     // 128 VGPR/wave, K-slice 256
        #pragma unroll
        for (int mt = 0; mt < 2; ++mt) {
            const int pr = (mt << 4) + m;
            const size_t rw = (size_t)(((pr & 3) << 10) + HO + (pr >> 2)) << 10;
            #pragma unroll
            for (int kt = 0; kt < 8; ++kt) {
                const int k = (wv << 8) + (kt << 5) + (quad << 3);
                const float* p = (k < 1024) ? (W_ih2 + rw + k)
                                            : (W_hh2 + rw + k - 1024);
                split8(p, wh[mt][kt], wl[mt][kt]);
            }
        }
        for (int idx = tid; idx < 8192; idx += 512) {    // gAcc init
            const int p = idx >> 8, b = idx & 255;
            gAcc[p * GSTR + b] = bp[p];
        }
        __syncthreads();
        float cr[4] = {0, 0, 0, 0};

        for (int it = 0; it <= Tsz; ++it) {
            const int parW = it & 1;
            const int parR = parW ^ 1;

            if (wv == 0 && it >= 2) {                    // out column t=it-2
                const float* pp = partials + (parW << 15) + (bx << 7);
                float s = pp[lane] + pp[lane + 64];
                s += __shfl_xor(s, 32); s += __shfl_xor(s, 16); s += __shfl_xor(s, 8);
                s += __shfl_xor(s, 4);  s += __shfl_xor(s, 2);  s += __shfl_xor(s, 1);
                if (lane == 0) out[(bx << 9) + (it - 2)] = bouts_s + s;
            }

            // gates2(it-1) += W2 . [h1(it-1); h2(it-2)]
            if (it >= 1) {
                const bool hi2 = (wv >= 4);
                const _Float16* bhB = hi2 ? HBUF(parW, 1, 0) : HBUF(parR, 0, 0);
                const _Float16* blB = hi2 ? HBUF(parW, 1, 1) : HBUF(parR, 0, 1);
                const int lo_off = ((wv & 3) << 12) + (lane << 3);
                #pragma unroll 2
                for (int bi = 0; bi < 16; ++bi) {
                    const int btl = (bi + (wv << 1)) & 15;
                    const _Float16* ph = bhB + (btl << 14) + lo_off;
                    const _Float16* pl = blB + (btl << 14) + lo_off;
                    f32x4 a0[2] = {(f32x4){0,0,0,0}, (f32x4){0,0,0,0}};
                    f32x4 a1[2] = {(f32x4){0,0,0,0}, (f32x4){0,0,0,0}};
                    half8 bh = *(const half8*)ph;
                    half8 bl = *(const half8*)pl;
                    #pragma unroll
                    for (int kt = 0; kt < 8; ++kt) {
                        half8 bhN, blN;
                        if (kt < 7) {
                            bhN = *(const half8*)(ph + ((kt + 1) << 9));
                            blN = *(const half8*)(pl + ((kt + 1) << 9));
                        }
                        MFMA_V(a0[0], wh[0][kt], bh);
                        MFMA_V(a1[0], wh[0][kt], bl);
                        MFMA_V(a1[0], wl[0][kt], bh);
                        MFMA_V(a0[1], wh[1][kt], bh);
                        MFMA_V(a1[1], wh[1][kt], bl);
                        MFMA_V(a1[1], wl[1][kt], bh);
                        bh = bhN; bl = blN;
                    }
                    const int col = (btl << 4) + m;
                    #pragma unroll
                    for (int mt = 0; mt < 2; ++mt)
                        #pragma unroll
                        for (int r = 0; r < 4; ++r)
                            atomicAdd(&gAcc[((mt << 4) + (quad << 2) + r) * GSTR + col],
                                      a0[mt][r] + a1[mt][r] * INV2048);
                }
            }

            __syncthreads();

            if (it >= 1) {             // layer-2 cell for t=it-1 -> h2(it-1) @parR
                half4 hhi, hlo;
                float po = 0.0f;
                #pragma unroll
                for (int j = 0; j < 4; ++j) {
                    const int p = (hg << 4) + (j << 2);
                    const float gi = gAcc[(p + 0) * GSTR + b_ep];
                    const float gf = gAcc[(p + 1) * GSTR + b_ep];
                    const float gg = gAcc[(p + 2) * GSTR + b_ep];
                    const float go = gAcc[(p + 3) * GSTR + b_ep];
                    const float c  = sigm(gf) * cr[j] + sigm(gi) * tanh_f(gg);
                    cr[j] = c;
                    const float hn = sigm(go) * tanh_f(c);
                    hhi[j] = (_Float16)hn;
                    hlo[j] = (_Float16)((hn - (float)hhi[j]) * 2048.0f);
                    po += hn * woutp[(hg << 2) + j];
                }
                *(half4*)(HBUF(parR, 1, 0) + wofs) = hhi;
                *(half4*)(HBUF(parR, 1, 1) + wofs) = hlo;
                poArr[hg * GSTR + b_ep] = po;
                #pragma unroll
                for (int p = (hg << 4); p < (hg << 4) + 16; ++p)
                    gAcc[p * GSTR + b_ep] = bp[p];
            }
            __syncthreads();
            if (it >= 1 && tid < 256) {   // partials[parR][b][rg]
                const float s = poArr[tid] + poArr[GSTR + tid];
                partials[(parR << 15) + (tid << 7) + rg] = s;
            }

            step_barrier(bar0, bar1, phase2, dummyv, bx, isLead, xcc, nLead,
                         (unsigned)(it + 1));
        }
    }

    // tail: out column t=511 (partials parity 1, written at it=512)
    if (wv == 0) {
        const float* pp = partials + (1 << 15) + (bx << 7);
        float s = pp[lane] + pp[lane + 64];
        s += __shfl_xor(s, 32); s += __shfl_xor(s, 16); s += __shfl_xor(s, 8);
        s += __shfl_xor(s, 4);  s += __shfl_xor(s, 2);  s += __shfl_xor(s, 1);
        if (lane == 0) out[(bx << 9) + (Tsz - 1)] = bouts_s + s;
    }
    #undef HBUF
}

// ---------------------------------------------------------------------------
extern "C" void kernel_launch(void* const* d_in, const int* in_sizes, int n_in,
                              void* d_out, int out_size, void* d_ws, size_t ws_size,
                              hipStream_t stream)
{
    const float* x     = (const float*)d_in[0];
    const float* W_ih1 = (const float*)d_in[1];
    const float* W_hh1 = (const float*)d_in[2];
    const float* b_ih1 = (const float*)d_in[3];
    const float* b_hh1 = (const float*)d_in[4];
    const float* W_ih2 = (const float*)d_in[5];
    const float* W_hh2 = (const float*)d_in[6];
    const float* b_ih2 = (const float*)d_in[7];
    const float* b_hh2 = (const float*)d_in[8];
    const float* W_out = (const float*)d_in[9];
    const float* b_out = (const float*)d_in[10];
    float* out = (float*)d_out;
    char*  ws  = (char*)d_ws;

    void* args[] = {
        (void*)&x,
        (void*)&W_ih1, (void*)&W_hh1, (void*)&b_ih1, (void*)&b_hh1,
        (void*)&W_ih2, (void*)&W_hh2, (void*)&b_ih2, (void*)&b_hh2,
        (void*)&W_out, (void*)&b_out, (void*)&out, (void*)&ws,
    };
    hipLaunchCooperativeKernel((const void*)lstm_persist,
                               dim3(256), dim3(512), args, 0, stream);
}